// Round 8
// baseline (180.613 us; speedup 1.0000x reference)
//
#include <hip/hip_runtime.h>
#include <stdint.h>

#define HW      16384   // 128*128
#define WIDTH   128
#define NTOPK   300
#define NLINES  10000
#define MPAD2   10240   // 40*256, for 256-tile GEMMs

typedef unsigned short u16;
typedef unsigned int   u32;
typedef unsigned long long u64;
typedef __bf16 bf16x8 __attribute__((ext_vector_type(8)));
typedef float  f32x4  __attribute__((ext_vector_type(4)));

__device__ __forceinline__ u16 f2bf(float f) {
  u32 x = __builtin_bit_cast(u32, f);
  x += 0x7FFFu + ((x >> 16) & 1u);
  return (u16)(x >> 16);
}
__device__ __forceinline__ float bf2f(u32 u) {
  return __builtin_bit_cast(float, u << 16);
}
__device__ __forceinline__ void gload_lds16(void* lds, const void* g) {
  __builtin_amdgcn_global_load_lds(
      (const __attribute__((address_space(1))) void*)g,
      (__attribute__((address_space(3))) void*)lds, 16, 0, 0);
}

#define CF asm volatile("" ::: "memory")
#define BAR do { CF; __builtin_amdgcn_s_barrier(); CF; } while (0)
#define VM4 asm volatile("s_waitcnt vmcnt(4)" ::: "memory")
#define VM0 asm volatile("s_waitcnt vmcnt(0)" ::: "memory")

// =============== k_front1: NMS-compact || featT transpose || weight cvt ===============
// blocks [0,64): sigmoid+3x3 NMS on 16x16 tile + halo; winners -> wkeys[b*256+pos], bcnt[b]
// blocks [64,1088): features [256c][16384p] f32 -> featT [16384p][256c] bf16
// blocks [1088,1608): f32->bf16 convert of w1 (256 blk), w2 (256 blk), fc1w (8 blk)
__global__ __launch_bounds__(256) void k_front1(const float* __restrict__ out9,
                                                const float* __restrict__ features,
                                                const float* __restrict__ w1,
                                                const float* __restrict__ w2,
                                                const float* __restrict__ fc1,
                                                u16* __restrict__ featT,
                                                u16* __restrict__ w1b,
                                                u16* __restrict__ w2b,
                                                u16* __restrict__ fc1wb,
                                                u64* __restrict__ wkeys,
                                                int* __restrict__ bcnt) {
  __shared__ float sm[64 * 65];    // 16.25 KB, aliased per role
  __shared__ int lcnt;
  int b = blockIdx.x, t = threadIdx.x;
  if (b < 64) {
    // ---- NMS-compact ----
    float (*jl)[18] = (float(*)[18])sm;
    if (t == 0) lcnt = 0;
    int bx = b & 7, by = b >> 3;
    int gx0 = bx * 16 - 1, gy0 = by * 16 - 1;
    for (int lin = t; lin < 324; lin += 256) {
      int lx = lin % 18, ly = lin / 18;
      int gx = gx0 + lx, gy = gy0 + ly;
      float v = -__builtin_inff();
      if (gx >= 0 && gx < WIDTH && gy >= 0 && gy < WIDTH) {
        int i = gy * WIDTH + gx;
        v = 1.f / (1.f + expf(out9[5 * HW + i] - out9[6 * HW + i]));
      }
      jl[ly][lx] = v;
    }
    __syncthreads();
    int tx = t & 15, ty = t >> 4;
    float a = jl[ty + 1][tx + 1], m = a;
#pragma unroll
    for (int dy = 0; dy < 3; ++dy)
#pragma unroll
      for (int dx = 0; dx < 3; ++dx)
        m = fmaxf(m, jl[ty + dy][tx + dx]);
    if (a == m) {                       // sigmoid > 0 always; winner iff local max
      int pos = atomicAdd(&lcnt, 1);
      int i = (by * 16 + ty) * WIDTH + bx * 16 + tx;
      wkeys[b * 256 + pos] =
          ((u64)__builtin_bit_cast(u32, a) << 32) | (u32)(0xFFFFFFFFu - (u32)i);
    }
    __syncthreads();
    if (t == 0) bcnt[b] = lcnt;
  } else if (b < 1088) {
    // ---- transpose ----
    float (*tile)[65] = (float(*)[65])sm;
    int bb = b - 64;
    int p0 = (bb & 255) * 64, c0 = (bb >> 8) * 64;
#pragma unroll
    for (int i = 0; i < 4; ++i) {
      int lin = i * 256 + t;
      int c = lin >> 4, p4 = (lin & 15) * 4;
      float4 v = *(const float4*)&features[(size_t)(c0 + c) * HW + p0 + p4];
      tile[c][p4 + 0] = v.x; tile[c][p4 + 1] = v.y;
      tile[c][p4 + 2] = v.z; tile[c][p4 + 3] = v.w;
    }
    __syncthreads();
#pragma unroll
    for (int i = 0; i < 2; ++i) {
      int lin = i * 256 + t;
      int p = lin >> 3, c8 = (lin & 7) * 8;
      uint4 pk;
      pk.x = (u32)f2bf(tile[c8 + 0][p]) | ((u32)f2bf(tile[c8 + 1][p]) << 16);
      pk.y = (u32)f2bf(tile[c8 + 2][p]) | ((u32)f2bf(tile[c8 + 3][p]) << 16);
      pk.z = (u32)f2bf(tile[c8 + 4][p]) | ((u32)f2bf(tile[c8 + 5][p]) << 16);
      pk.w = (u32)f2bf(tile[c8 + 6][p]) | ((u32)f2bf(tile[c8 + 7][p]) << 16);
      *(uint4*)&featT[(size_t)(p0 + p) * 256 + c0 + c8] = pk;
    }
  } else {
    // ---- weight convert ----
    int idx = b - 1088;
    const float* s; u16* d; int base;
    if (idx < 256)      { s = w1;  d = w1b;  base = idx * 4096; }
    else if (idx < 512) { s = w2;  d = w2b;  base = (idx - 256) * 4096; }
    else                { s = fc1; d = fc1wb; base = (idx - 512) * 4096; }
#pragma unroll
    for (int r = 0; r < 4; ++r) {
      int i = base + r * 1024 + t * 4;
      float4 v = *(const float4*)&s[i];
      uint2 pk;
      pk.x = (u32)f2bf(v.x) | ((u32)f2bf(v.y) << 16);
      pk.y = (u32)f2bf(v.z) | ((u32)f2bf(v.w) << 16);
      *(uint2*)&d[i] = pk;
    }
  }
}

// =============== k_front2: top-300 sort+emit (block 0) || loi GEMM (blocks 1..128) ===============
__global__ __launch_bounds__(256) void k_front2(const u64* __restrict__ wkeys,
                                                const int* __restrict__ bcnt,
                                                const float* __restrict__ out9,
                                                float* __restrict__ juncs_ws,
                                                float* __restrict__ out_juncs,
                                                float* __restrict__ out_jsc,
                                                const u16* __restrict__ featT,
                                                const u16* __restrict__ fc1wb,
                                                const float* __restrict__ fc1b,
                                                u16* __restrict__ loib) {
  __shared__ u64 smem[4096];     // 32 KB; sort keys / GEMM LDS alias
  __shared__ int lcnt;
  int t = threadIdx.x;
  if (blockIdx.x == 0) {
    // ---- gather winners, pad, bitonic sort desc, emit top-300 ----
    u64* keys = smem;
    if (t == 0) lcnt = 0;
    __syncthreads();
    for (int j = t; j < 64 * 256; j += 256) {
      int bb = j >> 8, ii = j & 255;
      if (ii < bcnt[bb]) {
        int pos = atomicAdd(&lcnt, 1);
        if (pos < 4096) keys[pos] = wkeys[j];
      }
    }
    __syncthreads();
    int c = lcnt < 4096 ? lcnt : 4096;
    int n = (c <= 2048) ? 2048 : 4096;   // expected ~1850; exact fallback kept
    for (int i = t; i < n; i += 256)
      if (i >= c) keys[i] = 0ull;
    __syncthreads();
    for (int k = 2; k <= n; k <<= 1) {
      for (int j = k >> 1; j > 0; j >>= 1) {
        for (int u = t; u < (n >> 1); u += 256) {
          int i  = ((u & ~(j - 1)) << 1) | (u & (j - 1));
          int p  = i | j;
          u64 a = keys[i], bkey = keys[p];
          bool dir = (i & k) == 0;
          if ((a < bkey) == dir) { keys[i] = bkey; keys[p] = a; }
        }
        __syncthreads();
      }
    }
    for (int i = t; i < NTOPK; i += 256) {
      u64 key = keys[i];
      u32 vb  = (u32)(key >> 32);
      int idx = (int)(0xFFFFFFFFu - (u32)(key & 0xFFFFFFFFu));
      float ox = 1.f / (1.f + expf(-out9[7 * HW + idx])) - 0.5f;
      float oy = 1.f / (1.f + expf(-out9[8 * HW + idx])) - 0.5f;
      float x = (float)(idx & (WIDTH - 1)) + ox + 0.5f;
      float y = (float)(idx >> 7)          + oy + 0.5f;
      juncs_ws[2 * i] = x; juncs_ws[2 * i + 1] = y;
      out_juncs[2 * i] = x; out_juncs[2 * i + 1] = y;
      out_jsc[i] = __builtin_bit_cast(float, vb);
    }
  } else {
    // ---- loi GEMM: loib[p][d] = featT[p][:] . fc1wb[d][:] + fc1b[d]  (M=HW,N=128,K=256)
    u16* Alds = (u16*)smem;            // 128*32 u16 = 8 KB
    u16* Blds = (u16*)smem + 4096;     // 8 KB
    const int K = 256, N = 128;
    int bid = blockIdx.x - 1;          // 0..127
    int key = (bid & 7) * 16 + (bid >> 3);   // bijective XCD swizzle, nwg=128
    int tm0 = key * 128;
    int lane = t & 63, wid = t >> 6;
    int wr = wid >> 1, wc = wid & 1;
    f32x4 acc[4][4] = {};
    int arow = t >> 2, apos = (t & 3) * 8;
    const u16* Abase = featT + (size_t)tm0 * K;
    int r = lane & 15, ks = (lane >> 4) * 8;
    for (int k0 = 0; k0 < K; k0 += 32) {
      gload_lds16(&Alds[(size_t)t * 8],         Abase + (size_t)arow * K + k0 + apos);
      gload_lds16(&Alds[(size_t)(t + 256) * 8], Abase + (size_t)(arow + 64) * K + k0 + apos);
      gload_lds16(&Blds[(size_t)t * 8],         fc1wb + (size_t)arow * K + k0 + apos);
      gload_lds16(&Blds[(size_t)(t + 256) * 8], fc1wb + (size_t)(arow + 64) * K + k0 + apos);
      __syncthreads();
      bf16x8 af[4], bfr[4];
#pragma unroll
      for (int i = 0; i < 4; ++i) {
        af[i]  = *(const bf16x8*)&Alds[(wr * 64 + i * 16 + r) * 32 + ks];
        bfr[i] = *(const bf16x8*)&Blds[(wc * 64 + i * 16 + r) * 32 + ks];
      }
#pragma unroll
      for (int mi = 0; mi < 4; ++mi)
#pragma unroll
        for (int ni = 0; ni < 4; ++ni)
          acc[mi][ni] = __builtin_amdgcn_mfma_f32_16x16x32_bf16(af[mi], bfr[ni], acc[mi][ni], 0, 0, 0);
      __syncthreads();
    }
    int rsub = (lane >> 4) * 4, csub = lane & 15;
#pragma unroll
    for (int mi = 0; mi < 4; ++mi) {
#pragma unroll
      for (int ni = 0; ni < 4; ++ni) {
        int col = wc * 64 + ni * 16 + csub;
        float bv = fc1b[col];
#pragma unroll
        for (int j = 0; j < 4; ++j) {
          int row = tm0 + wr * 64 + mi * 16 + rsub + j;
          loib[(size_t)row * N + col] = f2bf(acc[mi][ni][j] + bv);
        }
      }
    }
  }
}

// =============== stages 4+6 fused: match + line pooling ===============
__device__ __forceinline__ void acc8(uint4 r, float wg, float* a) {
  a[0] += bf2f(r.x & 0xffffu) * wg; a[1] += bf2f(r.x >> 16) * wg;
  a[2] += bf2f(r.y & 0xffffu) * wg; a[3] += bf2f(r.y >> 16) * wg;
  a[4] += bf2f(r.z & 0xffffu) * wg; a[5] += bf2f(r.z >> 16) * wg;
  a[6] += bf2f(r.w & 0xffffu) * wg; a[7] += bf2f(r.w >> 16) * wg;
}
__global__ __launch_bounds__(256) void k_minterp(const float* __restrict__ juncs,
                                                 const float* __restrict__ lines_pred,
                                                 const u16* __restrict__ loib,
                                                 float* __restrict__ lines_adj,
                                                 float* __restrict__ keepf,
                                                 u16* __restrict__ feat) {
  __shared__ float jl[2 * NTOPK];
  __shared__ u16 outb[4][8][128];
  int t = threadIdx.x;
  for (int i = t; i < 2 * NTOPK; i += 256) jl[i] = juncs[i];
  __syncthreads();
  int w = t >> 6, lane = t & 63;
  int l = blockIdx.x * 4 + w;
  float lx1 = lines_pred[l * 4 + 0], ly1 = lines_pred[l * 4 + 1];
  float lx2 = lines_pred[l * 4 + 2], ly2 = lines_pred[l * 4 + 3];
  float b1 = __builtin_inff(), b2 = __builtin_inff();
  int i1 = 0, i2 = 0;
  for (int j = lane; j < NTOPK; j += 64) {
    float jx = jl[2 * j], jy = jl[2 * j + 1];
    float dx = __fsub_rn(lx1, jx), dy = __fsub_rn(ly1, jy);
    float d  = __fadd_rn(__fmul_rn(dx, dx), __fmul_rn(dy, dy));
    if (d < b1) { b1 = d; i1 = j; }
    dx = __fsub_rn(lx2, jx); dy = __fsub_rn(ly2, jy);
    d  = __fadd_rn(__fmul_rn(dx, dx), __fmul_rn(dy, dy));
    if (d < b2) { b2 = d; i2 = j; }
  }
#pragma unroll
  for (int off = 1; off < 64; off <<= 1) {
    float d_o = __shfl_xor(b1, off, 64); int i_o = __shfl_xor(i1, off, 64);
    if (d_o < b1 || (d_o == b1 && i_o < i1)) { b1 = d_o; i1 = i_o; }
    d_o = __shfl_xor(b2, off, 64); i_o = __shfl_xor(i2, off, 64);
    if (d_o < b2 || (d_o == b2 && i_o < i2)) { b2 = d_o; i2 = i_o; }
  }
  int imin = i1 < i2 ? i1 : i2;
  int imax = i1 < i2 ? i2 : i1;
  float ux = jl[2 * imin], uy = jl[2 * imin + 1];
  float vx = jl[2 * imax], vy = jl[2 * imax + 1];
  if (lane == 0) {
    lines_adj[l * 4 + 0] = ux;
    lines_adj[l * 4 + 1] = uy;
    lines_adj[l * 4 + 2] = vx;
    lines_adj[l * 4 + 3] = vy;
    keepf[l] = (imin < imax) ? 1.f : 0.f;
  }
  int q = lane >> 4, chgrp = lane & 15, co = chgrp * 8;
#pragma unroll
  for (int s = 0; s < 8; ++s) {
    int p = s * 4 + q;
    float tt = (float)p / 31.f;
    float px = ux * tt + vx * (1.f - tt) - 0.5f;
    float py = uy * tt + vy * (1.f - tt) - 0.5f;
    float px0 = fminf(fmaxf(floorf(px), 0.f), 127.f);
    float py0 = fminf(fmaxf(floorf(py), 0.f), 127.f);
    float px1 = fminf(px0 + 1.f, 127.f);
    float py1 = fminf(py0 + 1.f, 127.f);
    int ix0 = (int)px0, iy0 = (int)py0, ix1 = (int)px1, iy1 = (int)py1;
    float wy1 = py1 - py, wy0 = py - py0, wx1 = px1 - px, wx0 = px - px0;
    uint4 v00 = *(const uint4*)&loib[(iy0 * WIDTH + ix0) * 128 + co];
    uint4 v10 = *(const uint4*)&loib[(iy1 * WIDTH + ix0) * 128 + co];
    uint4 v01 = *(const uint4*)&loib[(iy0 * WIDTH + ix1) * 128 + co];
    uint4 v11 = *(const uint4*)&loib[(iy1 * WIDTH + ix1) * 128 + co];
    float a[8];
#pragma unroll
    for (int cc = 0; cc < 8; ++cc) a[cc] = 0.f;
    acc8(v00, wy1 * wx1, a);
    acc8(v10, wy0 * wx1, a);
    acc8(v01, wy1 * wx0, a);
    acc8(v11, wy0 * wx0, a);
#pragma unroll
    for (int cc = 0; cc < 8; ++cc) {
      float v = fmaxf(a[cc], __shfl_xor(a[cc], 16, 64));
      v = fmaxf(v, __shfl_xor(v, 32, 64));
      a[cc] = v;
    }
    if (q == 0) {
      uint4 pk;
      pk.x = (u32)f2bf(a[0]) | ((u32)f2bf(a[1]) << 16);
      pk.y = (u32)f2bf(a[2]) | ((u32)f2bf(a[3]) << 16);
      pk.z = (u32)f2bf(a[4]) | ((u32)f2bf(a[5]) << 16);
      pk.w = (u32)f2bf(a[6]) | ((u32)f2bf(a[7]) << 16);
      *(uint4*)&outb[w][s][co] = pk;
    }
  }
  __syncthreads();
#pragma unroll
  for (int cc = 0; cc < 2; ++cc) {
    int ch = lane * 2 + cc;
    uint4 pk;
    pk.x = (u32)outb[w][0][ch] | ((u32)outb[w][1][ch] << 16);
    pk.y = (u32)outb[w][2][ch] | ((u32)outb[w][3][ch] << 16);
    pk.z = (u32)outb[w][4][ch] | ((u32)outb[w][5][ch] << 16);
    pk.w = (u32)outb[w][6][ch] | ((u32)outb[w][7][ch] << 16);
    *(uint4*)&feat[(size_t)l * 1024 + ch * 8] = pk;
  }
}

// =============== 256-tile 8-phase GEMM (T2+T3+T4+T5) — unchanged ===============
__device__ __forceinline__ void stg256(u16* S, int ldsbase, const u16* Xb,
                                       size_t sbase, int K, int kt, int h, int dbase) {
  gload_lds16(&S[ldsbase + h * 8192 + dbase],
              Xb + sbase + (size_t)(h * 128) * K + kt * 64);
  gload_lds16(&S[ldsbase + h * 8192 + 4096 + dbase],
              Xb + sbase + (size_t)(h * 128 + 64) * K + kt * 64);
}
template <int RH>
__device__ __forceinline__ void lda4(bf16x8 (*dst)[2], const u16* Sa, int rowA,
                                     int kx0, int kx1) {
#pragma unroll
  for (int f = 0; f < 4; ++f) {
    const u16* p = Sa + rowA + (RH * 64 + f * 16) * 64;
    dst[f][0] = *(const bf16x8*)&p[kx0];
    dst[f][1] = *(const bf16x8*)&p[kx1];
  }
}
template <int CH>
__device__ __forceinline__ void ldb2(bf16x8 (*dst)[2], const u16* Sb, int rowB,
                                     int kx0, int kx1) {
#pragma unroll
  for (int cf = 0; cf < 2; ++cf) {
    const u16* p = Sb + rowB + (CH * 32 + cf * 16) * 64;
    dst[cf][0] = *(const bf16x8*)&p[kx0];
    dst[cf][1] = *(const bf16x8*)&p[kx1];
  }
}
template <int RH, int CH>
__device__ __forceinline__ void mm16(f32x4 (*acc)[4], bf16x8 (*af)[2], bf16x8 (*bf)[2]) {
  __builtin_amdgcn_s_setprio(1);
#pragma unroll
  for (int f = 0; f < 4; ++f)
#pragma unroll
    for (int cf = 0; cf < 2; ++cf) {
      f32x4 a = acc[RH * 4 + f][CH * 2 + cf];
      a = __builtin_amdgcn_mfma_f32_16x16x32_bf16(af[f][0], bf[cf][0], a, 0, 0, 0);
      a = __builtin_amdgcn_mfma_f32_16x16x32_bf16(af[f][1], bf[cf][1], a, 0, 0, 0);
      acc[RH * 4 + f][CH * 2 + cf] = a;
    }
  __builtin_amdgcn_s_setprio(0);
}

template <int RELU, int HEAD>
__global__ __launch_bounds__(512, 2) void k_gemm256(const u16* __restrict__ A,
                                                    const u16* __restrict__ B,
                                                    const float* __restrict__ bias,
                                                    u16* __restrict__ C,
                                                    const float* __restrict__ w3,
                                                    float* __restrict__ partial,
                                                    int M, int N, int K) {
  __shared__ u16 S[65536];
  const int t = threadIdx.x, lane = t & 63, w = t >> 6;
  const int wm = w >> 2, wn = w & 3;
  int nwg = gridDim.x * gridDim.y;
  int bid = blockIdx.y * gridDim.x + blockIdx.x;
  int cpx = nwg >> 3;
  int key = (bid & 7) * cpx + (bid >> 3);
  int bx = key / gridDim.y, by = key % gridDim.y;
  const u16* Ab = A + (size_t)(bx * 256) * K;
  const u16* Bb = B + (size_t)(by * 256) * K;
  const int srow = w * 8 + (lane >> 3);
  const size_t sbase = (size_t)srow * K + ((lane & 7) ^ (lane >> 3)) * 8;
  const int dbase = w * 512 + lane * 8;
  const int l15 = lane & 15, hi = lane >> 4, l7 = lane & 7;
  const int rowA = (wm * 128 + l15) * 64;
  const int rowB = (wn * 64 + l15) * 64;
  const int kx0 = ((0 + hi) ^ l7) * 8;
  const int kx1 = ((4 + hi) ^ l7) * 8;
  const u16* SA0 = S;
  const u16* SA1 = S + 16384;
  const u16* SB0 = S + 32768;
  const u16* SB1 = S + 49152;
  f32x4 acc[8][4] = {};
  bf16x8 af0[4][2], af1[4][2], bf0[2][2], bf1[2][2];
  const int NI = K >> 7;
  stg256(S, 0,     Ab, sbase, K, 0, 0, dbase);
  stg256(S, 0,     Ab, sbase, K, 0, 1, dbase);
  stg256(S, 32768, Bb, sbase, K, 0, 0, dbase);
  stg256(S, 32768, Bb, sbase, K, 0, 1, dbase);
  stg256(S, 16384, Ab, sbase, K, 1, 0, dbase);
  stg256(S, 16384, Ab, sbase, K, 1, 1, dbase);
  VM4; BAR;
  for (int j = 0; j < NI - 1; ++j) {
    int kt = 2 * j;
    lda4<0>(af0, SA0, rowA, kx0, kx1);
    ldb2<0>(bf0, SB0, rowB, kx0, kx1);
    stg256(S, 49152, Bb, sbase, K, kt + 1, 0, dbase);
    BAR; mm16<0, 0>(acc, af0, bf0); BAR;
    lda4<1>(af1, SA0, rowA, kx0, kx1);
    stg256(S, 49152, Bb, sbase, K, kt + 1, 1, dbase);
    BAR; mm16<1, 0>(acc, af1, bf0); BAR;
    ldb2<1>(bf1, SB0, rowB, kx0, kx1);
    stg256(S, 0, Ab, sbase, K, kt + 2, 0, dbase);
    BAR; mm16<0, 1>(acc, af0, bf1); BAR;
    stg256(S, 0, Ab, sbase, K, kt + 2, 1, dbase);
    VM4;
    BAR; mm16<1, 1>(acc, af1, bf1); BAR;
    lda4<0>(af0, SA1, rowA, kx0, kx1);
    ldb2<0>(bf0, SB1, rowB, kx0, kx1);
    stg256(S, 32768, Bb, sbase, K, kt + 2, 0, dbase);
    BAR; mm16<0, 0>(acc, af0, bf0); BAR;
    lda4<1>(af1, SA1, rowA, kx0, kx1);
    stg256(S, 32768, Bb, sbase, K, kt + 2, 1, dbase);
    BAR; mm16<1, 0>(acc, af1, bf0); BAR;
    ldb2<1>(bf1, SB1, rowB, kx0, kx1);
    stg256(S, 16384, Ab, sbase, K, kt + 3, 0, dbase);
    BAR; mm16<0, 1>(acc, af0, bf1); BAR;
    stg256(S, 16384, Ab, sbase, K, kt + 3, 1, dbase);
    VM4;
    BAR; mm16<1, 1>(acc, af1, bf1); BAR;
  }
  {
    int kt = 2 * (NI - 1);
    lda4<0>(af0, SA0, rowA, kx0, kx1);
    ldb2<0>(bf0, SB0, rowB, kx0, kx1);
    stg256(S, 49152, Bb, sbase, K, kt + 1, 0, dbase);
    BAR; mm16<0, 0>(acc, af0, bf0); BAR;
    lda4<1>(af1, SA0, rowA, kx0, kx1);
    stg256(S, 49152, Bb, sbase, K, kt + 1, 1, dbase);
    BAR; mm16<1, 0>(acc, af1, bf0); BAR;
    ldb2<1>(bf1, SB0, rowB, kx0, kx1);
    BAR; mm16<0, 1>(acc, af0, bf1); BAR;
    VM0;
    BAR; mm16<1, 1>(acc, af1, bf1); BAR;
    lda4<0>(af0, SA1, rowA, kx0, kx1);
    ldb2<0>(bf0, SB1, rowB, kx0, kx1);
    BAR; mm16<0, 0>(acc, af0, bf0); BAR;
    lda4<1>(af1, SA1, rowA, kx0, kx1);
    BAR; mm16<1, 0>(acc, af1, bf0); BAR;
    ldb2<1>(bf1, SB1, rowB, kx0, kx1);
    BAR; mm16<0, 1>(acc, af0, bf1); BAR;
    mm16<1, 1>(acc, af1, bf1);
  }
  int row0 = bx * 256 + wm * 128 + hi * 4;
  int col0 = by * 256 + wn * 64 + l15;
  if (HEAD == 0) {
#pragma unroll
    for (int f = 0; f < 8; ++f) {
#pragma unroll
      for (int cf = 0; cf < 4; ++cf) {
        float bv = bias[col0 + cf * 16];
#pragma unroll
        for (int jj = 0; jj < 4; ++jj) {
          float v = acc[f][cf][jj] + bv;
          if (RELU) v = fmaxf(v, 0.f);
          C[(size_t)(row0 + f * 16 + jj) * N + col0 + cf * 16] = f2bf(v);
        }
      }
    }
  } else {
    float bv[4], wv[4];
#pragma unroll
    for (int cf = 0; cf < 4; ++cf) {
      bv[cf] = bias[col0 + cf * 16];
      wv[cf] = w3[col0 + cf * 16];
    }
#pragma unroll
    for (int f = 0; f < 8; ++f) {
#pragma unroll
      for (int jj = 0; jj < 4; ++jj) {
        float p = 0.f;
#pragma unroll
        for (int cf = 0; cf < 4; ++cf) {
          float v = acc[f][cf][jj] + bv[cf];
          v = fmaxf(v, 0.f);
          p += v * wv[cf];
        }
        p += __shfl_xor(p, 1, 64);
        p += __shfl_xor(p, 2, 64);
        p += __shfl_xor(p, 4, 64);
        p += __shfl_xor(p, 8, 64);
        if (l15 == 0)
          partial[(size_t)(by * 4 + wn) * M + row0 + f * 16 + jj] = p;
      }
    }
  }
}

// =============== stage 9: reduce 16 partials -> sigmoid * keep ===============
__global__ __launch_bounds__(256) void k_head2(const float* __restrict__ partial,
                                               const float* __restrict__ b3,
                                               const float* __restrict__ keepf,
                                               float* __restrict__ scores, int M) {
  int l = blockIdx.x * 256 + threadIdx.x;
  if (l >= NLINES) return;
  float s = 0.f;
#pragma unroll
  for (int i = 0; i < 16; ++i) s += partial[(size_t)i * M + l];
  float logit = s + b3[0];
  scores[l] = keepf[l] / (1.f + expf(-logit));
}

extern "C" void kernel_launch(void* const* d_in, const int* in_sizes, int n_in,
                              void* d_out, int out_size, void* d_ws, size_t ws_size,
                              hipStream_t stream) {
  const float* t_output   = (const float*)d_in[0];
  const float* t_features = (const float*)d_in[1];
  const float* t_lines    = (const float*)d_in[2];
  const float* t_fc1w     = (const float*)d_in[3];
  const float* t_fc1b     = (const float*)d_in[4];
  const float* t_w1       = (const float*)d_in[5];
  const float* t_b1       = (const float*)d_in[6];
  const float* t_w2       = (const float*)d_in[7];
  const float* t_b2       = (const float*)d_in[8];
  const float* t_w3       = (const float*)d_in[9];
  const float* t_b3       = (const float*)d_in[10];

  // workspace layout (~49.5 MB)
  char* w = (char*)d_ws;
  u16*   loib  = (u16*)w;                         // 4 MB
  float* juncs = (float*)(w + 4194304);           // 1024 f32
  float* keepf = juncs + 1024;                    // 10240 f32
  int*   bcnt  = (int*)(keepf + 10240);           // 256 int
  u64*   wkeys = (u64*)(bcnt + 256);              // 16384 u64 = 128 KB
  u16* fc1wb = (u16*)(wkeys + 16384);             // 32768 bf16
  u16* w1b  = fc1wb + 32768;                      // 1M bf16
  u16* w2b  = w1b + 1048576;
  u16* feat = w2b + 1048576;                      // MPAD2*1024 bf16 = 20 MB
  u16* hid1 = feat + (size_t)MPAD2 * 1024;        // 20 MB
  float* partial = (float*)(hid1 + (size_t)MPAD2 * 1024);  // 16*MPAD2 f32
  u16* featT = hid1;                              // alias: consumed before gemm256#1 writes hid1

  float* out_scores = (float*)d_out;
  float* out_ladj   = out_scores + NLINES;
  float* out_juncs  = out_scores + 50000;
  float* out_jsc    = out_scores + 50600;

  k_front1<<<1608, 256, 0, stream>>>(t_output, t_features, t_w1, t_w2, t_fc1w,
                                     featT, w1b, w2b, fc1wb, wkeys, bcnt);
  k_front2<<<129, 256, 0, stream>>>(wkeys, bcnt, t_output,
                                    juncs, out_juncs, out_jsc,
                                    featT, fc1wb, t_fc1b, loib);
  k_minterp<<<2500, 256, 0, stream>>>(juncs, t_lines, loib, out_ladj, keepf, feat);
  k_gemm256<1, 0><<<dim3(40, 4), 512, 0, stream>>>(feat, w1b, t_b1, hid1,
                                                   nullptr, nullptr, MPAD2, 1024, 1024);
  k_gemm256<0, 1><<<dim3(40, 4), 512, 0, stream>>>(hid1, w2b, t_b2, nullptr,
                                                   t_w3, partial, MPAD2, 1024, 1024);
  k_head2<<<40, 256, 0, stream>>>(partial, t_b3, keepf, out_scores, MPAD2);
}

// Round 9
// 165.131 us; speedup vs baseline: 1.0938x; 1.0938x over previous
//
#include <hip/hip_runtime.h>
#include <stdint.h>

#define HW      16384   // 128*128
#define WIDTH   128
#define NTOPK   300
#define NLINES  10000
#define MPAD2   10240   // 40*256, for 256-tile GEMMs

typedef unsigned short u16;
typedef unsigned int   u32;
typedef unsigned long long u64;
typedef __bf16 bf16x8 __attribute__((ext_vector_type(8)));
typedef float  f32x4  __attribute__((ext_vector_type(4)));

__device__ __forceinline__ u16 f2bf(float f) {
  u32 x = __builtin_bit_cast(u32, f);
  x += 0x7FFFu + ((x >> 16) & 1u);
  return (u16)(x >> 16);
}
__device__ __forceinline__ float bf2f(u32 u) {
  return __builtin_bit_cast(float, u << 16);
}
__device__ __forceinline__ void gload_lds16(void* lds, const void* g) {
  __builtin_amdgcn_global_load_lds(
      (const __attribute__((address_space(1))) void*)g,
      (__attribute__((address_space(3))) void*)lds, 16, 0, 0);
}

#define CF asm volatile("" ::: "memory")
#define BAR do { CF; __builtin_amdgcn_s_barrier(); CF; } while (0)
#define VM4 asm volatile("s_waitcnt vmcnt(4)" ::: "memory")
#define VM0 asm volatile("s_waitcnt vmcnt(0)" ::: "memory")

// =============== k_front1: NMS-compact || featT transpose || weight cvt ===============
__global__ __launch_bounds__(256) void k_front1(const float* __restrict__ out9,
                                                const float* __restrict__ features,
                                                const float* __restrict__ w1,
                                                const float* __restrict__ w2,
                                                const float* __restrict__ fc1,
                                                u16* __restrict__ featT,
                                                u16* __restrict__ w1b,
                                                u16* __restrict__ w2b,
                                                u16* __restrict__ fc1wb,
                                                u64* __restrict__ wkeys,
                                                int* __restrict__ bcnt) {
  __shared__ float sm[64 * 65];
  __shared__ int lcnt;
  int b = blockIdx.x, t = threadIdx.x;
  if (b < 64) {
    // ---- NMS-compact ----
    float (*jl)[18] = (float(*)[18])sm;
    if (t == 0) lcnt = 0;
    int bx = b & 7, by = b >> 3;
    int gx0 = bx * 16 - 1, gy0 = by * 16 - 1;
    for (int lin = t; lin < 324; lin += 256) {
      int lx = lin % 18, ly = lin / 18;
      int gx = gx0 + lx, gy = gy0 + ly;
      float v = -__builtin_inff();
      if (gx >= 0 && gx < WIDTH && gy >= 0 && gy < WIDTH) {
        int i = gy * WIDTH + gx;
        v = 1.f / (1.f + expf(out9[5 * HW + i] - out9[6 * HW + i]));
      }
      jl[ly][lx] = v;
    }
    __syncthreads();
    int tx = t & 15, ty = t >> 4;
    float a = jl[ty + 1][tx + 1], m = a;
#pragma unroll
    for (int dy = 0; dy < 3; ++dy)
#pragma unroll
      for (int dx = 0; dx < 3; ++dx)
        m = fmaxf(m, jl[ty + dy][tx + dx]);
    if (a == m) {
      int pos = atomicAdd(&lcnt, 1);
      int i = (by * 16 + ty) * WIDTH + bx * 16 + tx;
      wkeys[b * 256 + pos] =
          ((u64)__builtin_bit_cast(u32, a) << 32) | (u32)(0xFFFFFFFFu - (u32)i);
    }
    __syncthreads();
    if (t == 0) bcnt[b] = lcnt;
  } else if (b < 1088) {
    // ---- transpose ----
    float (*tile)[65] = (float(*)[65])sm;
    int bb = b - 64;
    int p0 = (bb & 255) * 64, c0 = (bb >> 8) * 64;
#pragma unroll
    for (int i = 0; i < 4; ++i) {
      int lin = i * 256 + t;
      int c = lin >> 4, p4 = (lin & 15) * 4;
      float4 v = *(const float4*)&features[(size_t)(c0 + c) * HW + p0 + p4];
      tile[c][p4 + 0] = v.x; tile[c][p4 + 1] = v.y;
      tile[c][p4 + 2] = v.z; tile[c][p4 + 3] = v.w;
    }
    __syncthreads();
#pragma unroll
    for (int i = 0; i < 2; ++i) {
      int lin = i * 256 + t;
      int p = lin >> 3, c8 = (lin & 7) * 8;
      uint4 pk;
      pk.x = (u32)f2bf(tile[c8 + 0][p]) | ((u32)f2bf(tile[c8 + 1][p]) << 16);
      pk.y = (u32)f2bf(tile[c8 + 2][p]) | ((u32)f2bf(tile[c8 + 3][p]) << 16);
      pk.z = (u32)f2bf(tile[c8 + 4][p]) | ((u32)f2bf(tile[c8 + 5][p]) << 16);
      pk.w = (u32)f2bf(tile[c8 + 6][p]) | ((u32)f2bf(tile[c8 + 7][p]) << 16);
      *(uint4*)&featT[(size_t)(p0 + p) * 256 + c0 + c8] = pk;
    }
  } else {
    // ---- weight convert ----
    int idx = b - 1088;
    const float* s; u16* d; int base;
    if (idx < 256)      { s = w1;  d = w1b;  base = idx * 4096; }
    else if (idx < 512) { s = w2;  d = w2b;  base = (idx - 256) * 4096; }
    else                { s = fc1; d = fc1wb; base = (idx - 512) * 4096; }
#pragma unroll
    for (int r = 0; r < 4; ++r) {
      int i = base + r * 1024 + t * 4;
      float4 v = *(const float4*)&s[i];
      uint2 pk;
      pk.x = (u32)f2bf(v.x) | ((u32)f2bf(v.y) << 16);
      pk.y = (u32)f2bf(v.z) | ((u32)f2bf(v.w) << 16);
      *(uint2*)&d[i] = pk;
    }
  }
}

// =============== k_front2 (1024 thr): sort block 0 || loi GEMM blocks 1..128 ===============
// Block 0: segment-gather valid winners (no dead-slot scan), 1024-thread bitonic, emit.
// Blocks 1-128: gemm on waves 0-3 (t<256); waves 4-15 match the 16 __syncthreads.
__global__ __launch_bounds__(1024) void k_front2(const u64* __restrict__ wkeys,
                                                 const int* __restrict__ bcnt,
                                                 const float* __restrict__ out9,
                                                 float* __restrict__ juncs_ws,
                                                 float* __restrict__ out_juncs,
                                                 float* __restrict__ out_jsc,
                                                 const u16* __restrict__ featT,
                                                 const u16* __restrict__ fc1wb,
                                                 const float* __restrict__ fc1b,
                                                 u16* __restrict__ loib) {
  __shared__ u64 smem[4096];     // 32 KB: sort keys / GEMM LDS alias
  __shared__ int scnt[64];
  __shared__ int sbase[65];
  int t = threadIdx.x;
  if (blockIdx.x == 0) {
    u64* keys = smem;
    if (t < 64) scnt[t] = bcnt[t];
    __syncthreads();
    if (t == 0) {
      int s = 0;
      for (int bb = 0; bb < 64; ++bb) { sbase[bb] = s; s += scnt[bb]; }
      sbase[64] = s < 4096 ? s : 4096;
    }
    __syncthreads();
    int total = sbase[64];
    // copy only valid segments (coalesced, pipelined)
    for (int bb = 0; bb < 64; ++bb) {
      int base = sbase[bb], c = scnt[bb];
      for (int i = t; i < c; i += 1024) {
        int d = base + i;
        if (d < 4096) keys[d] = wkeys[bb * 256 + i];
      }
    }
    __syncthreads();
    int n = (total <= 2048) ? 2048 : 4096;
    for (int i = t; i < n; i += 1024)
      if (i >= total) keys[i] = 0ull;
    __syncthreads();
    for (int k = 2; k <= n; k <<= 1) {
      for (int j = k >> 1; j > 0; j >>= 1) {
        for (int u = t; u < (n >> 1); u += 1024) {
          int i  = ((u & ~(j - 1)) << 1) | (u & (j - 1));
          int p  = i | j;
          u64 a = keys[i], bkey = keys[p];
          bool dir = (i & k) == 0;
          if ((a < bkey) == dir) { keys[i] = bkey; keys[p] = a; }
        }
        __syncthreads();
      }
    }
    if (t < NTOPK) {
      u64 key = keys[t];
      u32 vb  = (u32)(key >> 32);
      int idx = (int)(0xFFFFFFFFu - (u32)(key & 0xFFFFFFFFu));
      float ox = 1.f / (1.f + expf(-out9[7 * HW + idx])) - 0.5f;
      float oy = 1.f / (1.f + expf(-out9[8 * HW + idx])) - 0.5f;
      float x = (float)(idx & (WIDTH - 1)) + ox + 0.5f;
      float y = (float)(idx >> 7)          + oy + 0.5f;
      juncs_ws[2 * t] = x; juncs_ws[2 * t + 1] = y;
      out_juncs[2 * t] = x; out_juncs[2 * t + 1] = y;
      out_jsc[t] = __builtin_bit_cast(float, vb);
    }
  } else {
    if (t < 256) {
      // ---- loi GEMM (proven m97 structure): M=HW, N=128, K=256 ----
      u16* Alds = (u16*)smem;            // 8 KB
      u16* Blds = (u16*)smem + 4096;     // 8 KB
      const int K = 256, N = 128;
      int bid = blockIdx.x - 1;
      int key = (bid & 7) * 16 + (bid >> 3);   // bijective XCD swizzle, nwg=128
      int tm0 = key * 128;
      int lane = t & 63, wid = t >> 6;
      int wr = wid >> 1, wc = wid & 1;
      f32x4 acc[4][4] = {};
      int arow = t >> 2, apos = (t & 3) * 8;
      const u16* Abase = featT + (size_t)tm0 * K;
      int r = lane & 15, ks = (lane >> 4) * 8;
      for (int k0 = 0; k0 < K; k0 += 32) {
        gload_lds16(&Alds[(size_t)t * 8],         Abase + (size_t)arow * K + k0 + apos);
        gload_lds16(&Alds[(size_t)(t + 256) * 8], Abase + (size_t)(arow + 64) * K + k0 + apos);
        gload_lds16(&Blds[(size_t)t * 8],         fc1wb + (size_t)arow * K + k0 + apos);
        gload_lds16(&Blds[(size_t)(t + 256) * 8], fc1wb + (size_t)(arow + 64) * K + k0 + apos);
        __syncthreads();
        bf16x8 af[4], bfr[4];
#pragma unroll
        for (int i = 0; i < 4; ++i) {
          af[i]  = *(const bf16x8*)&Alds[(wr * 64 + i * 16 + r) * 32 + ks];
          bfr[i] = *(const bf16x8*)&Blds[(wc * 64 + i * 16 + r) * 32 + ks];
        }
#pragma unroll
        for (int mi = 0; mi < 4; ++mi)
#pragma unroll
          for (int ni = 0; ni < 4; ++ni)
            acc[mi][ni] = __builtin_amdgcn_mfma_f32_16x16x32_bf16(af[mi], bfr[ni], acc[mi][ni], 0, 0, 0);
        __syncthreads();
      }
      int rsub = (lane >> 4) * 4, csub = lane & 15;
#pragma unroll
      for (int mi = 0; mi < 4; ++mi) {
#pragma unroll
        for (int ni = 0; ni < 4; ++ni) {
          int col = wc * 64 + ni * 16 + csub;
          float bv = fc1b[col];
#pragma unroll
          for (int j = 0; j < 4; ++j) {
            int row = tm0 + wr * 64 + mi * 16 + rsub + j;
            loib[(size_t)row * N + col] = f2bf(acc[mi][ni][j] + bv);
          }
        }
      }
    } else {
      // idle waves: match the active path's 16 barriers exactly
      for (int i = 0; i < 16; ++i) __syncthreads();
    }
  }
}

// =============== stages 4+6 fused: match + line pooling ===============
__device__ __forceinline__ void acc8(uint4 r, float wg, float* a) {
  a[0] += bf2f(r.x & 0xffffu) * wg; a[1] += bf2f(r.x >> 16) * wg;
  a[2] += bf2f(r.y & 0xffffu) * wg; a[3] += bf2f(r.y >> 16) * wg;
  a[4] += bf2f(r.z & 0xffffu) * wg; a[5] += bf2f(r.z >> 16) * wg;
  a[6] += bf2f(r.w & 0xffffu) * wg; a[7] += bf2f(r.w >> 16) * wg;
}
__global__ __launch_bounds__(256) void k_minterp(const float* __restrict__ juncs,
                                                 const float* __restrict__ lines_pred,
                                                 const u16* __restrict__ loib,
                                                 float* __restrict__ lines_adj,
                                                 float* __restrict__ keepf,
                                                 u16* __restrict__ feat) {
  __shared__ float jl[2 * NTOPK];
  __shared__ u16 outb[4][8][128];
  int t = threadIdx.x;
  for (int i = t; i < 2 * NTOPK; i += 256) jl[i] = juncs[i];
  __syncthreads();
  int w = t >> 6, lane = t & 63;
  int l = blockIdx.x * 4 + w;
  float lx1 = lines_pred[l * 4 + 0], ly1 = lines_pred[l * 4 + 1];
  float lx2 = lines_pred[l * 4 + 2], ly2 = lines_pred[l * 4 + 3];
  float b1 = __builtin_inff(), b2 = __builtin_inff();
  int i1 = 0, i2 = 0;
  for (int j = lane; j < NTOPK; j += 64) {
    float jx = jl[2 * j], jy = jl[2 * j + 1];
    float dx = __fsub_rn(lx1, jx), dy = __fsub_rn(ly1, jy);
    float d  = __fadd_rn(__fmul_rn(dx, dx), __fmul_rn(dy, dy));
    if (d < b1) { b1 = d; i1 = j; }
    dx = __fsub_rn(lx2, jx); dy = __fsub_rn(ly2, jy);
    d  = __fadd_rn(__fmul_rn(dx, dx), __fmul_rn(dy, dy));
    if (d < b2) { b2 = d; i2 = j; }
  }
#pragma unroll
  for (int off = 1; off < 64; off <<= 1) {
    float d_o = __shfl_xor(b1, off, 64); int i_o = __shfl_xor(i1, off, 64);
    if (d_o < b1 || (d_o == b1 && i_o < i1)) { b1 = d_o; i1 = i_o; }
    d_o = __shfl_xor(b2, off, 64); i_o = __shfl_xor(i2, off, 64);
    if (d_o < b2 || (d_o == b2 && i_o < i2)) { b2 = d_o; i2 = i_o; }
  }
  int imin = i1 < i2 ? i1 : i2;
  int imax = i1 < i2 ? i2 : i1;
  float ux = jl[2 * imin], uy = jl[2 * imin + 1];
  float vx = jl[2 * imax], vy = jl[2 * imax + 1];
  if (lane == 0) {
    lines_adj[l * 4 + 0] = ux;
    lines_adj[l * 4 + 1] = uy;
    lines_adj[l * 4 + 2] = vx;
    lines_adj[l * 4 + 3] = vy;
    keepf[l] = (imin < imax) ? 1.f : 0.f;
  }
  int q = lane >> 4, chgrp = lane & 15, co = chgrp * 8;
#pragma unroll
  for (int s = 0; s < 8; ++s) {
    int p = s * 4 + q;
    float tt = (float)p / 31.f;
    float px = ux * tt + vx * (1.f - tt) - 0.5f;
    float py = uy * tt + vy * (1.f - tt) - 0.5f;
    float px0 = fminf(fmaxf(floorf(px), 0.f), 127.f);
    float py0 = fminf(fmaxf(floorf(py), 0.f), 127.f);
    float px1 = fminf(px0 + 1.f, 127.f);
    float py1 = fminf(py0 + 1.f, 127.f);
    int ix0 = (int)px0, iy0 = (int)py0, ix1 = (int)px1, iy1 = (int)py1;
    float wy1 = py1 - py, wy0 = py - py0, wx1 = px1 - px, wx0 = px - px0;
    uint4 v00 = *(const uint4*)&loib[(iy0 * WIDTH + ix0) * 128 + co];
    uint4 v10 = *(const uint4*)&loib[(iy1 * WIDTH + ix0) * 128 + co];
    uint4 v01 = *(const uint4*)&loib[(iy0 * WIDTH + ix1) * 128 + co];
    uint4 v11 = *(const uint4*)&loib[(iy1 * WIDTH + ix1) * 128 + co];
    float a[8];
#pragma unroll
    for (int cc = 0; cc < 8; ++cc) a[cc] = 0.f;
    acc8(v00, wy1 * wx1, a);
    acc8(v10, wy0 * wx1, a);
    acc8(v01, wy1 * wx0, a);
    acc8(v11, wy0 * wx0, a);
#pragma unroll
    for (int cc = 0; cc < 8; ++cc) {
      float v = fmaxf(a[cc], __shfl_xor(a[cc], 16, 64));
      v = fmaxf(v, __shfl_xor(v, 32, 64));
      a[cc] = v;
    }
    if (q == 0) {
      uint4 pk;
      pk.x = (u32)f2bf(a[0]) | ((u32)f2bf(a[1]) << 16);
      pk.y = (u32)f2bf(a[2]) | ((u32)f2bf(a[3]) << 16);
      pk.z = (u32)f2bf(a[4]) | ((u32)f2bf(a[5]) << 16);
      pk.w = (u32)f2bf(a[6]) | ((u32)f2bf(a[7]) << 16);
      *(uint4*)&outb[w][s][co] = pk;
    }
  }
  __syncthreads();
#pragma unroll
  for (int cc = 0; cc < 2; ++cc) {
    int ch = lane * 2 + cc;
    uint4 pk;
    pk.x = (u32)outb[w][0][ch] | ((u32)outb[w][1][ch] << 16);
    pk.y = (u32)outb[w][2][ch] | ((u32)outb[w][3][ch] << 16);
    pk.z = (u32)outb[w][4][ch] | ((u32)outb[w][5][ch] << 16);
    pk.w = (u32)outb[w][6][ch] | ((u32)outb[w][7][ch] << 16);
    *(uint4*)&feat[(size_t)l * 1024 + ch * 8] = pk;
  }
}

// =============== 256-tile 8-phase GEMM (T2+T3+T4+T5) — unchanged ===============
__device__ __forceinline__ void stg256(u16* S, int ldsbase, const u16* Xb,
                                       size_t sbase, int K, int kt, int h, int dbase) {
  gload_lds16(&S[ldsbase + h * 8192 + dbase],
              Xb + sbase + (size_t)(h * 128) * K + kt * 64);
  gload_lds16(&S[ldsbase + h * 8192 + 4096 + dbase],
              Xb + sbase + (size_t)(h * 128 + 64) * K + kt * 64);
}
template <int RH>
__device__ __forceinline__ void lda4(bf16x8 (*dst)[2], const u16* Sa, int rowA,
                                     int kx0, int kx1) {
#pragma unroll
  for (int f = 0; f < 4; ++f) {
    const u16* p = Sa + rowA + (RH * 64 + f * 16) * 64;
    dst[f][0] = *(const bf16x8*)&p[kx0];
    dst[f][1] = *(const bf16x8*)&p[kx1];
  }
}
template <int CH>
__device__ __forceinline__ void ldb2(bf16x8 (*dst)[2], const u16* Sb, int rowB,
                                     int kx0, int kx1) {
#pragma unroll
  for (int cf = 0; cf < 2; ++cf) {
    const u16* p = Sb + rowB + (CH * 32 + cf * 16) * 64;
    dst[cf][0] = *(const bf16x8*)&p[kx0];
    dst[cf][1] = *(const bf16x8*)&p[kx1];
  }
}
template <int RH, int CH>
__device__ __forceinline__ void mm16(f32x4 (*acc)[4], bf16x8 (*af)[2], bf16x8 (*bf)[2]) {
  __builtin_amdgcn_s_setprio(1);
#pragma unroll
  for (int f = 0; f < 4; ++f)
#pragma unroll
    for (int cf = 0; cf < 2; ++cf) {
      f32x4 a = acc[RH * 4 + f][CH * 2 + cf];
      a = __builtin_amdgcn_mfma_f32_16x16x32_bf16(af[f][0], bf[cf][0], a, 0, 0, 0);
      a = __builtin_amdgcn_mfma_f32_16x16x32_bf16(af[f][1], bf[cf][1], a, 0, 0, 0);
      acc[RH * 4 + f][CH * 2 + cf] = a;
    }
  __builtin_amdgcn_s_setprio(0);
}

template <int RELU, int HEAD>
__global__ __launch_bounds__(512, 2) void k_gemm256(const u16* __restrict__ A,
                                                    const u16* __restrict__ B,
                                                    const float* __restrict__ bias,
                                                    u16* __restrict__ C,
                                                    const float* __restrict__ w3,
                                                    float* __restrict__ partial,
                                                    int M, int N, int K) {
  __shared__ u16 S[65536];
  const int t = threadIdx.x, lane = t & 63, w = t >> 6;
  const int wm = w >> 2, wn = w & 3;
  int nwg = gridDim.x * gridDim.y;
  int bid = blockIdx.y * gridDim.x + blockIdx.x;
  int cpx = nwg >> 3;
  int key = (bid & 7) * cpx + (bid >> 3);
  int bx = key / gridDim.y, by = key % gridDim.y;
  const u16* Ab = A + (size_t)(bx * 256) * K;
  const u16* Bb = B + (size_t)(by * 256) * K;
  const int srow = w * 8 + (lane >> 3);
  const size_t sbase = (size_t)srow * K + ((lane & 7) ^ (lane >> 3)) * 8;
  const int dbase = w * 512 + lane * 8;
  const int l15 = lane & 15, hi = lane >> 4, l7 = lane & 7;
  const int rowA = (wm * 128 + l15) * 64;
  const int rowB = (wn * 64 + l15) * 64;
  const int kx0 = ((0 + hi) ^ l7) * 8;
  const int kx1 = ((4 + hi) ^ l7) * 8;
  const u16* SA0 = S;
  const u16* SA1 = S + 16384;
  const u16* SB0 = S + 32768;
  const u16* SB1 = S + 49152;
  f32x4 acc[8][4] = {};
  bf16x8 af0[4][2], af1[4][2], bf0[2][2], bf1[2][2];
  const int NI = K >> 7;
  stg256(S, 0,     Ab, sbase, K, 0, 0, dbase);
  stg256(S, 0,     Ab, sbase, K, 0, 1, dbase);
  stg256(S, 32768, Bb, sbase, K, 0, 0, dbase);
  stg256(S, 32768, Bb, sbase, K, 0, 1, dbase);
  stg256(S, 16384, Ab, sbase, K, 1, 0, dbase);
  stg256(S, 16384, Ab, sbase, K, 1, 1, dbase);
  VM4; BAR;
  for (int j = 0; j < NI - 1; ++j) {
    int kt = 2 * j;
    lda4<0>(af0, SA0, rowA, kx0, kx1);
    ldb2<0>(bf0, SB0, rowB, kx0, kx1);
    stg256(S, 49152, Bb, sbase, K, kt + 1, 0, dbase);
    BAR; mm16<0, 0>(acc, af0, bf0); BAR;
    lda4<1>(af1, SA0, rowA, kx0, kx1);
    stg256(S, 49152, Bb, sbase, K, kt + 1, 1, dbase);
    BAR; mm16<1, 0>(acc, af1, bf0); BAR;
    ldb2<1>(bf1, SB0, rowB, kx0, kx1);
    stg256(S, 0, Ab, sbase, K, kt + 2, 0, dbase);
    BAR; mm16<0, 1>(acc, af0, bf1); BAR;
    stg256(S, 0, Ab, sbase, K, kt + 2, 1, dbase);
    VM4;
    BAR; mm16<1, 1>(acc, af1, bf1); BAR;
    lda4<0>(af0, SA1, rowA, kx0, kx1);
    ldb2<0>(bf0, SB1, rowB, kx0, kx1);
    stg256(S, 32768, Bb, sbase, K, kt + 2, 0, dbase);
    BAR; mm16<0, 0>(acc, af0, bf0); BAR;
    lda4<1>(af1, SA1, rowA, kx0, kx1);
    stg256(S, 32768, Bb, sbase, K, kt + 2, 1, dbase);
    BAR; mm16<1, 0>(acc, af1, bf0); BAR;
    ldb2<1>(bf1, SB1, rowB, kx0, kx1);
    stg256(S, 16384, Ab, sbase, K, kt + 3, 0, dbase);
    BAR; mm16<0, 1>(acc, af0, bf1); BAR;
    stg256(S, 16384, Ab, sbase, K, kt + 3, 1, dbase);
    VM4;
    BAR; mm16<1, 1>(acc, af1, bf1); BAR;
  }
  {
    int kt = 2 * (NI - 1);
    lda4<0>(af0, SA0, rowA, kx0, kx1);
    ldb2<0>(bf0, SB0, rowB, kx0, kx1);
    stg256(S, 49152, Bb, sbase, K, kt + 1, 0, dbase);
    BAR; mm16<0, 0>(acc, af0, bf0); BAR;
    lda4<1>(af1, SA0, rowA, kx0, kx1);
    stg256(S, 49152, Bb, sbase, K, kt + 1, 1, dbase);
    BAR; mm16<1, 0>(acc, af1, bf0); BAR;
    ldb2<1>(bf1, SB0, rowB, kx0, kx1);
    BAR; mm16<0, 1>(acc, af0, bf1); BAR;
    VM0;
    BAR; mm16<1, 1>(acc, af1, bf1); BAR;
    lda4<0>(af0, SA1, rowA, kx0, kx1);
    ldb2<0>(bf0, SB1, rowB, kx0, kx1);
    BAR; mm16<0, 0>(acc, af0, bf0); BAR;
    lda4<1>(af1, SA1, rowA, kx0, kx1);
    BAR; mm16<1, 0>(acc, af1, bf0); BAR;
    ldb2<1>(bf1, SB1, rowB, kx0, kx1);
    BAR; mm16<0, 1>(acc, af0, bf1); BAR;
    mm16<1, 1>(acc, af1, bf1);
  }
  int row0 = bx * 256 + wm * 128 + hi * 4;
  int col0 = by * 256 + wn * 64 + l15;
  if (HEAD == 0) {
#pragma unroll
    for (int f = 0; f < 8; ++f) {
#pragma unroll
      for (int cf = 0; cf < 4; ++cf) {
        float bv = bias[col0 + cf * 16];
#pragma unroll
        for (int jj = 0; jj < 4; ++jj) {
          float v = acc[f][cf][jj] + bv;
          if (RELU) v = fmaxf(v, 0.f);
          C[(size_t)(row0 + f * 16 + jj) * N + col0 + cf * 16] = f2bf(v);
        }
      }
    }
  } else {
    float bv[4], wv[4];
#pragma unroll
    for (int cf = 0; cf < 4; ++cf) {
      bv[cf] = bias[col0 + cf * 16];
      wv[cf] = w3[col0 + cf * 16];
    }
#pragma unroll
    for (int f = 0; f < 8; ++f) {
#pragma unroll
      for (int jj = 0; jj < 4; ++jj) {
        float p = 0.f;
#pragma unroll
        for (int cf = 0; cf < 4; ++cf) {
          float v = acc[f][cf][jj] + bv[cf];
          v = fmaxf(v, 0.f);
          p += v * wv[cf];
        }
        p += __shfl_xor(p, 1, 64);
        p += __shfl_xor(p, 2, 64);
        p += __shfl_xor(p, 4, 64);
        p += __shfl_xor(p, 8, 64);
        if (l15 == 0)
          partial[(size_t)(by * 4 + wn) * M + row0 + f * 16 + jj] = p;
      }
    }
  }
}

// =============== stage 9: reduce 16 partials -> sigmoid * keep ===============
__global__ __launch_bounds__(256) void k_head2(const float* __restrict__ partial,
                                               const float* __restrict__ b3,
                                               const float* __restrict__ keepf,
                                               float* __restrict__ scores, int M) {
  int l = blockIdx.x * 256 + threadIdx.x;
  if (l >= NLINES) return;
  float s = 0.f;
#pragma unroll
  for (int i = 0; i < 16; ++i) s += partial[(size_t)i * M + l];
  float logit = s + b3[0];
  scores[l] = keepf[l] / (1.f + expf(-logit));
}

extern "C" void kernel_launch(void* const* d_in, const int* in_sizes, int n_in,
                              void* d_out, int out_size, void* d_ws, size_t ws_size,
                              hipStream_t stream) {
  const float* t_output   = (const float*)d_in[0];
  const float* t_features = (const float*)d_in[1];
  const float* t_lines    = (const float*)d_in[2];
  const float* t_fc1w     = (const float*)d_in[3];
  const float* t_fc1b     = (const float*)d_in[4];
  const float* t_w1       = (const float*)d_in[5];
  const float* t_b1       = (const float*)d_in[6];
  const float* t_w2       = (const float*)d_in[7];
  const float* t_b2       = (const float*)d_in[8];
  const float* t_w3       = (const float*)d_in[9];
  const float* t_b3       = (const float*)d_in[10];

  // workspace layout (~49.5 MB)
  char* w = (char*)d_ws;
  u16*   loib  = (u16*)w;                         // 4 MB
  float* juncs = (float*)(w + 4194304);           // 1024 f32
  float* keepf = juncs + 1024;                    // 10240 f32
  int*   bcnt  = (int*)(keepf + 10240);           // 256 int
  u64*   wkeys = (u64*)(bcnt + 256);              // 16384 u64 = 128 KB
  u16* fc1wb = (u16*)(wkeys + 16384);             // 32768 bf16
  u16* w1b  = fc1wb + 32768;                      // 1M bf16
  u16* w2b  = w1b + 1048576;
  u16* feat = w2b + 1048576;                      // MPAD2*1024 bf16 = 20 MB
  u16* hid1 = feat + (size_t)MPAD2 * 1024;        // 20 MB
  float* partial = (float*)(hid1 + (size_t)MPAD2 * 1024);  // 16*MPAD2 f32
  u16* featT = hid1;                              // alias: consumed before gemm256#1 writes hid1

  float* out_scores = (float*)d_out;
  float* out_ladj   = out_scores + NLINES;
  float* out_juncs  = out_scores + 50000;
  float* out_jsc    = out_scores + 50600;

  k_front1<<<1608, 256, 0, stream>>>(t_output, t_features, t_w1, t_w2, t_fc1w,
                                     featT, w1b, w2b, fc1wb, wkeys, bcnt);
  k_front2<<<129, 1024, 0, stream>>>(wkeys, bcnt, t_output,
                                     juncs, out_juncs, out_jsc,
                                     featT, fc1wb, t_fc1b, loib);
  k_minterp<<<2500, 256, 0, stream>>>(juncs, t_lines, loib, out_ladj, keepf, feat);
  k_gemm256<1, 0><<<dim3(40, 4), 512, 0, stream>>>(feat, w1b, t_b1, hid1,
                                                   nullptr, nullptr, MPAD2, 1024, 1024);
  k_gemm256<0, 1><<<dim3(40, 4), 512, 0, stream>>>(hid1, w2b, t_b2, nullptr,
                                                   t_w3, partial, MPAD2, 1024, 1024);
  k_head2<<<40, 256, 0, stream>>>(partial, t_b3, keepf, out_scores, MPAD2);
}

// Round 10
// 145.272 us; speedup vs baseline: 1.2433x; 1.1367x over previous
//
#include <hip/hip_runtime.h>
#include <stdint.h>

#define HW      16384   // 128*128
#define WIDTH   128
#define NTOPK   300
#define NLINES  10000
#define MPAD2   10240   // 40*256, for 256-tile GEMMs

typedef unsigned short u16;
typedef unsigned int   u32;
typedef unsigned long long u64;
typedef __bf16 bf16x8 __attribute__((ext_vector_type(8)));
typedef float  f32x4  __attribute__((ext_vector_type(4)));

__device__ __forceinline__ u16 f2bf(float f) {
  u32 x = __builtin_bit_cast(u32, f);
  x += 0x7FFFu + ((x >> 16) & 1u);
  return (u16)(x >> 16);
}
__device__ __forceinline__ float bf2f(u32 u) {
  return __builtin_bit_cast(float, u << 16);
}
__device__ __forceinline__ void gload_lds16(void* lds, const void* g) {
  __builtin_amdgcn_global_load_lds(
      (const __attribute__((address_space(1))) void*)g,
      (__attribute__((address_space(3))) void*)lds, 16, 0, 0);
}

#define CF asm volatile("" ::: "memory")
#define BAR do { CF; __builtin_amdgcn_s_barrier(); CF; } while (0)
#define VM4 asm volatile("s_waitcnt vmcnt(4)" ::: "memory")
#define VM0 asm volatile("s_waitcnt vmcnt(0)" ::: "memory")

// bank-spread swizzle for u64 sort keys: bijective (only low-4 bits XORed with
// a function of higher bits); kills same-bank aliasing at power-of-2 strides.
__device__ __forceinline__ int SIDX(int i) {
  return i ^ (((i >> 4) ^ (i >> 8)) & 15);
}

// =============== k_front1: NMS-compact || featT transpose || weight cvt ===============
__global__ __launch_bounds__(256) void k_front1(const float* __restrict__ out9,
                                                const float* __restrict__ features,
                                                const float* __restrict__ w1,
                                                const float* __restrict__ w2,
                                                const float* __restrict__ fc1,
                                                u16* __restrict__ featT,
                                                u16* __restrict__ w1b,
                                                u16* __restrict__ w2b,
                                                u16* __restrict__ fc1wb,
                                                u64* __restrict__ wkeys,
                                                int* __restrict__ bcnt) {
  __shared__ float sm[64 * 65];
  __shared__ int lcnt;
  int b = blockIdx.x, t = threadIdx.x;
  if (b < 64) {
    // ---- NMS-compact ----
    float (*jl)[18] = (float(*)[18])sm;
    if (t == 0) lcnt = 0;
    int bx = b & 7, by = b >> 3;
    int gx0 = bx * 16 - 1, gy0 = by * 16 - 1;
    for (int lin = t; lin < 324; lin += 256) {
      int lx = lin % 18, ly = lin / 18;
      int gx = gx0 + lx, gy = gy0 + ly;
      float v = -__builtin_inff();
      if (gx >= 0 && gx < WIDTH && gy >= 0 && gy < WIDTH) {
        int i = gy * WIDTH + gx;
        v = 1.f / (1.f + expf(out9[5 * HW + i] - out9[6 * HW + i]));
      }
      jl[ly][lx] = v;
    }
    __syncthreads();
    int tx = t & 15, ty = t >> 4;
    float a = jl[ty + 1][tx + 1], m = a;
#pragma unroll
    for (int dy = 0; dy < 3; ++dy)
#pragma unroll
      for (int dx = 0; dx < 3; ++dx)
        m = fmaxf(m, jl[ty + dy][tx + dx]);
    if (a == m) {
      int pos = atomicAdd(&lcnt, 1);
      int i = (by * 16 + ty) * WIDTH + bx * 16 + tx;
      wkeys[b * 256 + pos] =
          ((u64)__builtin_bit_cast(u32, a) << 32) | (u32)(0xFFFFFFFFu - (u32)i);
    }
    __syncthreads();
    if (t == 0) bcnt[b] = lcnt;
  } else if (b < 1088) {
    // ---- transpose ----
    float (*tile)[65] = (float(*)[65])sm;
    int bb = b - 64;
    int p0 = (bb & 255) * 64, c0 = (bb >> 8) * 64;
#pragma unroll
    for (int i = 0; i < 4; ++i) {
      int lin = i * 256 + t;
      int c = lin >> 4, p4 = (lin & 15) * 4;
      float4 v = *(const float4*)&features[(size_t)(c0 + c) * HW + p0 + p4];
      tile[c][p4 + 0] = v.x; tile[c][p4 + 1] = v.y;
      tile[c][p4 + 2] = v.z; tile[c][p4 + 3] = v.w;
    }
    __syncthreads();
#pragma unroll
    for (int i = 0; i < 2; ++i) {
      int lin = i * 256 + t;
      int p = lin >> 3, c8 = (lin & 7) * 8;
      uint4 pk;
      pk.x = (u32)f2bf(tile[c8 + 0][p]) | ((u32)f2bf(tile[c8 + 1][p]) << 16);
      pk.y = (u32)f2bf(tile[c8 + 2][p]) | ((u32)f2bf(tile[c8 + 3][p]) << 16);
      pk.z = (u32)f2bf(tile[c8 + 4][p]) | ((u32)f2bf(tile[c8 + 5][p]) << 16);
      pk.w = (u32)f2bf(tile[c8 + 6][p]) | ((u32)f2bf(tile[c8 + 7][p]) << 16);
      *(uint4*)&featT[(size_t)(p0 + p) * 256 + c0 + c8] = pk;
    }
  } else {
    // ---- weight convert ----
    int idx = b - 1088;
    const float* s; u16* d; int base;
    if (idx < 256)      { s = w1;  d = w1b;  base = idx * 4096; }
    else if (idx < 512) { s = w2;  d = w2b;  base = (idx - 256) * 4096; }
    else                { s = fc1; d = fc1wb; base = (idx - 512) * 4096; }
#pragma unroll
    for (int r = 0; r < 4; ++r) {
      int i = base + r * 1024 + t * 4;
      float4 v = *(const float4*)&s[i];
      uint2 pk;
      pk.x = (u32)f2bf(v.x) | ((u32)f2bf(v.y) << 16);
      pk.y = (u32)f2bf(v.z) | ((u32)f2bf(v.w) << 16);
      *(uint2*)&d[i] = pk;
    }
  }
}

// =============== k_front2 (1024 thr): sort block 0 || loi GEMM blocks 1..128 ===============
// Block 0: wave-parallel segment gather -> SIDX-swizzled LDS -> bitonic -> emit.
// Blocks 1-128: gemm on waves 0-3 (t<256); waves 4-15 match the 16 __syncthreads.
__global__ __launch_bounds__(1024) void k_front2(const u64* __restrict__ wkeys,
                                                 const int* __restrict__ bcnt,
                                                 const float* __restrict__ out9,
                                                 float* __restrict__ juncs_ws,
                                                 float* __restrict__ out_juncs,
                                                 float* __restrict__ out_jsc,
                                                 const u16* __restrict__ featT,
                                                 const u16* __restrict__ fc1wb,
                                                 const float* __restrict__ fc1b,
                                                 u16* __restrict__ loib) {
  __shared__ u64 smem[4096];     // 32 KB: sort keys / GEMM LDS alias
  __shared__ int scnt[64];
  __shared__ int sbase[65];
  int t = threadIdx.x;
  if (blockIdx.x == 0) {
    u64* keys = smem;
    if (t < 64) scnt[t] = bcnt[t];
    __syncthreads();
    if (t == 0) {
      int s = 0;
      for (int bb = 0; bb < 64; ++bb) { sbase[bb] = s; s += scnt[bb]; }
      sbase[64] = s < 4096 ? s : 4096;
    }
    __syncthreads();
    int total = sbase[64];
    // wave-parallel gather of valid segments (wave w owns bb = w, w+16, w+32, w+48)
    int wv = t >> 6, lane = t & 63;
    for (int bb = wv; bb < 64; bb += 16) {
      int base = sbase[bb], c = scnt[bb];
      for (int i = lane; i < c; i += 64) {
        int d = base + i;
        if (d < 4096) keys[SIDX(d)] = wkeys[bb * 256 + i];
      }
    }
    __syncthreads();
    int n = (total <= 2048) ? 2048 : 4096;
    for (int i = t; i < n; i += 1024)
      if (i >= total) keys[SIDX(i)] = 0ull;
    __syncthreads();
    for (int k = 2; k <= n; k <<= 1) {
      for (int j = k >> 1; j > 0; j >>= 1) {
        for (int u = t; u < (n >> 1); u += 1024) {
          int i  = ((u & ~(j - 1)) << 1) | (u & (j - 1));
          int p  = i | j;
          int si = SIDX(i), sp = SIDX(p);
          u64 a = keys[si], bkey = keys[sp];
          bool dir = (i & k) == 0;
          if ((a < bkey) == dir) { keys[si] = bkey; keys[sp] = a; }
        }
        __syncthreads();
      }
    }
    if (t < NTOPK) {
      u64 key = keys[SIDX(t)];
      u32 vb  = (u32)(key >> 32);
      int idx = (int)(0xFFFFFFFFu - (u32)(key & 0xFFFFFFFFu));
      float ox = 1.f / (1.f + expf(-out9[7 * HW + idx])) - 0.5f;
      float oy = 1.f / (1.f + expf(-out9[8 * HW + idx])) - 0.5f;
      float x = (float)(idx & (WIDTH - 1)) + ox + 0.5f;
      float y = (float)(idx >> 7)          + oy + 0.5f;
      juncs_ws[2 * t] = x; juncs_ws[2 * t + 1] = y;
      out_juncs[2 * t] = x; out_juncs[2 * t + 1] = y;
      out_jsc[t] = __builtin_bit_cast(float, vb);
    }
  } else {
    if (t < 256) {
      // ---- loi GEMM (proven m97 structure): M=HW, N=128, K=256 ----
      u16* Alds = (u16*)smem;            // 8 KB
      u16* Blds = (u16*)smem + 4096;     // 8 KB
      const int K = 256, N = 128;
      int bid = blockIdx.x - 1;
      int key = (bid & 7) * 16 + (bid >> 3);   // bijective XCD swizzle, nwg=128
      int tm0 = key * 128;
      int lane = t & 63, wid = t >> 6;
      int wr = wid >> 1, wc = wid & 1;
      f32x4 acc[4][4] = {};
      int arow = t >> 2, apos = (t & 3) * 8;
      const u16* Abase = featT + (size_t)tm0 * K;
      int r = lane & 15, ks = (lane >> 4) * 8;
      for (int k0 = 0; k0 < K; k0 += 32) {
        gload_lds16(&Alds[(size_t)t * 8],         Abase + (size_t)arow * K + k0 + apos);
        gload_lds16(&Alds[(size_t)(t + 256) * 8], Abase + (size_t)(arow + 64) * K + k0 + apos);
        gload_lds16(&Blds[(size_t)t * 8],         fc1wb + (size_t)arow * K + k0 + apos);
        gload_lds16(&Blds[(size_t)(t + 256) * 8], fc1wb + (size_t)(arow + 64) * K + k0 + apos);
        __syncthreads();
        bf16x8 af[4], bfr[4];
#pragma unroll
        for (int i = 0; i < 4; ++i) {
          af[i]  = *(const bf16x8*)&Alds[(wr * 64 + i * 16 + r) * 32 + ks];
          bfr[i] = *(const bf16x8*)&Blds[(wc * 64 + i * 16 + r) * 32 + ks];
        }
#pragma unroll
        for (int mi = 0; mi < 4; ++mi)
#pragma unroll
          for (int ni = 0; ni < 4; ++ni)
            acc[mi][ni] = __builtin_amdgcn_mfma_f32_16x16x32_bf16(af[mi], bfr[ni], acc[mi][ni], 0, 0, 0);
        __syncthreads();
      }
      int rsub = (lane >> 4) * 4, csub = lane & 15;
#pragma unroll
      for (int mi = 0; mi < 4; ++mi) {
#pragma unroll
        for (int ni = 0; ni < 4; ++ni) {
          int col = wc * 64 + ni * 16 + csub;
          float bv = fc1b[col];
#pragma unroll
          for (int j = 0; j < 4; ++j) {
            int row = tm0 + wr * 64 + mi * 16 + rsub + j;
            loib[(size_t)row * N + col] = f2bf(acc[mi][ni][j] + bv);
          }
        }
      }
    } else {
      // idle waves: match the active path's 16 barriers exactly
      for (int i = 0; i < 16; ++i) __syncthreads();
    }
  }
}

// =============== stages 4+6 fused: match + line pooling ===============
__device__ __forceinline__ void acc8(uint4 r, float wg, float* a) {
  a[0] += bf2f(r.x & 0xffffu) * wg; a[1] += bf2f(r.x >> 16) * wg;
  a[2] += bf2f(r.y & 0xffffu) * wg; a[3] += bf2f(r.y >> 16) * wg;
  a[4] += bf2f(r.z & 0xffffu) * wg; a[5] += bf2f(r.z >> 16) * wg;
  a[6] += bf2f(r.w & 0xffffu) * wg; a[7] += bf2f(r.w >> 16) * wg;
}
__global__ __launch_bounds__(256) void k_minterp(const float* __restrict__ juncs,
                                                 const float* __restrict__ lines_pred,
                                                 const u16* __restrict__ loib,
                                                 float* __restrict__ lines_adj,
                                                 float* __restrict__ keepf,
                                                 u16* __restrict__ feat) {
  __shared__ float jl[2 * NTOPK];
  __shared__ u16 outb[4][8][128];
  int t = threadIdx.x;
  for (int i = t; i < 2 * NTOPK; i += 256) jl[i] = juncs[i];
  __syncthreads();
  int w = t >> 6, lane = t & 63;
  int l = blockIdx.x * 4 + w;
  float lx1 = lines_pred[l * 4 + 0], ly1 = lines_pred[l * 4 + 1];
  float lx2 = lines_pred[l * 4 + 2], ly2 = lines_pred[l * 4 + 3];
  float b1 = __builtin_inff(), b2 = __builtin_inff();
  int i1 = 0, i2 = 0;
  for (int j = lane; j < NTOPK; j += 64) {
    float jx = jl[2 * j], jy = jl[2 * j + 1];
    float dx = __fsub_rn(lx1, jx), dy = __fsub_rn(ly1, jy);
    float d  = __fadd_rn(__fmul_rn(dx, dx), __fmul_rn(dy, dy));
    if (d < b1) { b1 = d; i1 = j; }
    dx = __fsub_rn(lx2, jx); dy = __fsub_rn(ly2, jy);
    d  = __fadd_rn(__fmul_rn(dx, dx), __fmul_rn(dy, dy));
    if (d < b2) { b2 = d; i2 = j; }
  }
#pragma unroll
  for (int off = 1; off < 64; off <<= 1) {
    float d_o = __shfl_xor(b1, off, 64); int i_o = __shfl_xor(i1, off, 64);
    if (d_o < b1 || (d_o == b1 && i_o < i1)) { b1 = d_o; i1 = i_o; }
    d_o = __shfl_xor(b2, off, 64); i_o = __shfl_xor(i2, off, 64);
    if (d_o < b2 || (d_o == b2 && i_o < i2)) { b2 = d_o; i2 = i_o; }
  }
  int imin = i1 < i2 ? i1 : i2;
  int imax = i1 < i2 ? i2 : i1;
  float ux = jl[2 * imin], uy = jl[2 * imin + 1];
  float vx = jl[2 * imax], vy = jl[2 * imax + 1];
  if (lane == 0) {
    lines_adj[l * 4 + 0] = ux;
    lines_adj[l * 4 + 1] = uy;
    lines_adj[l * 4 + 2] = vx;
    lines_adj[l * 4 + 3] = vy;
    keepf[l] = (imin < imax) ? 1.f : 0.f;
  }
  int q = lane >> 4, chgrp = lane & 15, co = chgrp * 8;
#pragma unroll
  for (int s = 0; s < 8; ++s) {
    int p = s * 4 + q;
    float tt = (float)p / 31.f;
    float px = ux * tt + vx * (1.f - tt) - 0.5f;
    float py = uy * tt + vy * (1.f - tt) - 0.5f;
    float px0 = fminf(fmaxf(floorf(px), 0.f), 127.f);
    float py0 = fminf(fmaxf(floorf(py), 0.f), 127.f);
    float px1 = fminf(px0 + 1.f, 127.f);
    float py1 = fminf(py0 + 1.f, 127.f);
    int ix0 = (int)px0, iy0 = (int)py0, ix1 = (int)px1, iy1 = (int)py1;
    float wy1 = py1 - py, wy0 = py - py0, wx1 = px1 - px, wx0 = px - px0;
    uint4 v00 = *(const uint4*)&loib[(iy0 * WIDTH + ix0) * 128 + co];
    uint4 v10 = *(const uint4*)&loib[(iy1 * WIDTH + ix0) * 128 + co];
    uint4 v01 = *(const uint4*)&loib[(iy0 * WIDTH + ix1) * 128 + co];
    uint4 v11 = *(const uint4*)&loib[(iy1 * WIDTH + ix1) * 128 + co];
    float a[8];
#pragma unroll
    for (int cc = 0; cc < 8; ++cc) a[cc] = 0.f;
    acc8(v00, wy1 * wx1, a);
    acc8(v10, wy0 * wx1, a);
    acc8(v01, wy1 * wx0, a);
    acc8(v11, wy0 * wx0, a);
#pragma unroll
    for (int cc = 0; cc < 8; ++cc) {
      float v = fmaxf(a[cc], __shfl_xor(a[cc], 16, 64));
      v = fmaxf(v, __shfl_xor(v, 32, 64));
      a[cc] = v;
    }
    if (q == 0) {
      uint4 pk;
      pk.x = (u32)f2bf(a[0]) | ((u32)f2bf(a[1]) << 16);
      pk.y = (u32)f2bf(a[2]) | ((u32)f2bf(a[3]) << 16);
      pk.z = (u32)f2bf(a[4]) | ((u32)f2bf(a[5]) << 16);
      pk.w = (u32)f2bf(a[6]) | ((u32)f2bf(a[7]) << 16);
      *(uint4*)&outb[w][s][co] = pk;
    }
  }
  __syncthreads();
#pragma unroll
  for (int cc = 0; cc < 2; ++cc) {
    int ch = lane * 2 + cc;
    uint4 pk;
    pk.x = (u32)outb[w][0][ch] | ((u32)outb[w][1][ch] << 16);
    pk.y = (u32)outb[w][2][ch] | ((u32)outb[w][3][ch] << 16);
    pk.z = (u32)outb[w][4][ch] | ((u32)outb[w][5][ch] << 16);
    pk.w = (u32)outb[w][6][ch] | ((u32)outb[w][7][ch] << 16);
    *(uint4*)&feat[(size_t)l * 1024 + ch * 8] = pk;
  }
}

// =============== 256-tile 8-phase GEMM (T2+T3+T4+T5) — unchanged ===============
__device__ __forceinline__ void stg256(u16* S, int ldsbase, const u16* Xb,
                                       size_t sbase, int K, int kt, int h, int dbase) {
  gload_lds16(&S[ldsbase + h * 8192 + dbase],
              Xb + sbase + (size_t)(h * 128) * K + kt * 64);
  gload_lds16(&S[ldsbase + h * 8192 + 4096 + dbase],
              Xb + sbase + (size_t)(h * 128 + 64) * K + kt * 64);
}
template <int RH>
__device__ __forceinline__ void lda4(bf16x8 (*dst)[2], const u16* Sa, int rowA,
                                     int kx0, int kx1) {
#pragma unroll
  for (int f = 0; f < 4; ++f) {
    const u16* p = Sa + rowA + (RH * 64 + f * 16) * 64;
    dst[f][0] = *(const bf16x8*)&p[kx0];
    dst[f][1] = *(const bf16x8*)&p[kx1];
  }
}
template <int CH>
__device__ __forceinline__ void ldb2(bf16x8 (*dst)[2], const u16* Sb, int rowB,
                                     int kx0, int kx1) {
#pragma unroll
  for (int cf = 0; cf < 2; ++cf) {
    const u16* p = Sb + rowB + (CH * 32 + cf * 16) * 64;
    dst[cf][0] = *(const bf16x8*)&p[kx0];
    dst[cf][1] = *(const bf16x8*)&p[kx1];
  }
}
template <int RH, int CH>
__device__ __forceinline__ void mm16(f32x4 (*acc)[4], bf16x8 (*af)[2], bf16x8 (*bf)[2]) {
  __builtin_amdgcn_s_setprio(1);
#pragma unroll
  for (int f = 0; f < 4; ++f)
#pragma unroll
    for (int cf = 0; cf < 2; ++cf) {
      f32x4 a = acc[RH * 4 + f][CH * 2 + cf];
      a = __builtin_amdgcn_mfma_f32_16x16x32_bf16(af[f][0], bf[cf][0], a, 0, 0, 0);
      a = __builtin_amdgcn_mfma_f32_16x16x32_bf16(af[f][1], bf[cf][1], a, 0, 0, 0);
      acc[RH * 4 + f][CH * 2 + cf] = a;
    }
  __builtin_amdgcn_s_setprio(0);
}

template <int RELU, int HEAD>
__global__ __launch_bounds__(512, 2) void k_gemm256(const u16* __restrict__ A,
                                                    const u16* __restrict__ B,
                                                    const float* __restrict__ bias,
                                                    u16* __restrict__ C,
                                                    const float* __restrict__ w3,
                                                    float* __restrict__ partial,
                                                    int M, int N, int K) {
  __shared__ u16 S[65536];
  const int t = threadIdx.x, lane = t & 63, w = t >> 6;
  const int wm = w >> 2, wn = w & 3;
  int nwg = gridDim.x * gridDim.y;
  int bid = blockIdx.y * gridDim.x + blockIdx.x;
  int cpx = nwg >> 3;
  int key = (bid & 7) * cpx + (bid >> 3);
  int bx = key / gridDim.y, by = key % gridDim.y;
  const u16* Ab = A + (size_t)(bx * 256) * K;
  const u16* Bb = B + (size_t)(by * 256) * K;
  const int srow = w * 8 + (lane >> 3);
  const size_t sbase = (size_t)srow * K + ((lane & 7) ^ (lane >> 3)) * 8;
  const int dbase = w * 512 + lane * 8;
  const int l15 = lane & 15, hi = lane >> 4, l7 = lane & 7;
  const int rowA = (wm * 128 + l15) * 64;
  const int rowB = (wn * 64 + l15) * 64;
  const int kx0 = ((0 + hi) ^ l7) * 8;
  const int kx1 = ((4 + hi) ^ l7) * 8;
  const u16* SA0 = S;
  const u16* SA1 = S + 16384;
  const u16* SB0 = S + 32768;
  const u16* SB1 = S + 49152;
  f32x4 acc[8][4] = {};
  bf16x8 af0[4][2], af1[4][2], bf0[2][2], bf1[2][2];
  const int NI = K >> 7;
  stg256(S, 0,     Ab, sbase, K, 0, 0, dbase);
  stg256(S, 0,     Ab, sbase, K, 0, 1, dbase);
  stg256(S, 32768, Bb, sbase, K, 0, 0, dbase);
  stg256(S, 32768, Bb, sbase, K, 0, 1, dbase);
  stg256(S, 16384, Ab, sbase, K, 1, 0, dbase);
  stg256(S, 16384, Ab, sbase, K, 1, 1, dbase);
  VM4; BAR;
  for (int j = 0; j < NI - 1; ++j) {
    int kt = 2 * j;
    lda4<0>(af0, SA0, rowA, kx0, kx1);
    ldb2<0>(bf0, SB0, rowB, kx0, kx1);
    stg256(S, 49152, Bb, sbase, K, kt + 1, 0, dbase);
    BAR; mm16<0, 0>(acc, af0, bf0); BAR;
    lda4<1>(af1, SA0, rowA, kx0, kx1);
    stg256(S, 49152, Bb, sbase, K, kt + 1, 1, dbase);
    BAR; mm16<1, 0>(acc, af1, bf0); BAR;
    ldb2<1>(bf1, SB0, rowB, kx0, kx1);
    stg256(S, 0, Ab, sbase, K, kt + 2, 0, dbase);
    BAR; mm16<0, 1>(acc, af0, bf1); BAR;
    stg256(S, 0, Ab, sbase, K, kt + 2, 1, dbase);
    VM4;
    BAR; mm16<1, 1>(acc, af1, bf1); BAR;
    lda4<0>(af0, SA1, rowA, kx0, kx1);
    ldb2<0>(bf0, SB1, rowB, kx0, kx1);
    stg256(S, 32768, Bb, sbase, K, kt + 2, 0, dbase);
    BAR; mm16<0, 0>(acc, af0, bf0); BAR;
    lda4<1>(af1, SA1, rowA, kx0, kx1);
    stg256(S, 32768, Bb, sbase, K, kt + 2, 1, dbase);
    BAR; mm16<1, 0>(acc, af1, bf0); BAR;
    ldb2<1>(bf1, SB1, rowB, kx0, kx1);
    stg256(S, 16384, Ab, sbase, K, kt + 3, 0, dbase);
    BAR; mm16<0, 1>(acc, af0, bf1); BAR;
    stg256(S, 16384, Ab, sbase, K, kt + 3, 1, dbase);
    VM4;
    BAR; mm16<1, 1>(acc, af1, bf1); BAR;
  }
  {
    int kt = 2 * (NI - 1);
    lda4<0>(af0, SA0, rowA, kx0, kx1);
    ldb2<0>(bf0, SB0, rowB, kx0, kx1);
    stg256(S, 49152, Bb, sbase, K, kt + 1, 0, dbase);
    BAR; mm16<0, 0>(acc, af0, bf0); BAR;
    lda4<1>(af1, SA0, rowA, kx0, kx1);
    stg256(S, 49152, Bb, sbase, K, kt + 1, 1, dbase);
    BAR; mm16<1, 0>(acc, af1, bf0); BAR;
    ldb2<1>(bf1, SB0, rowB, kx0, kx1);
    BAR; mm16<0, 1>(acc, af0, bf1); BAR;
    VM0;
    BAR; mm16<1, 1>(acc, af1, bf1); BAR;
    lda4<0>(af0, SA1, rowA, kx0, kx1);
    ldb2<0>(bf0, SB1, rowB, kx0, kx1);
    BAR; mm16<0, 0>(acc, af0, bf0); BAR;
    lda4<1>(af1, SA1, rowA, kx0, kx1);
    BAR; mm16<1, 0>(acc, af1, bf0); BAR;
    ldb2<1>(bf1, SB1, rowB, kx0, kx1);
    BAR; mm16<0, 1>(acc, af0, bf1); BAR;
    mm16<1, 1>(acc, af1, bf1);
  }
  int row0 = bx * 256 + wm * 128 + hi * 4;
  int col0 = by * 256 + wn * 64 + l15;
  if (HEAD == 0) {
#pragma unroll
    for (int f = 0; f < 8; ++f) {
#pragma unroll
      for (int cf = 0; cf < 4; ++cf) {
        float bv = bias[col0 + cf * 16];
#pragma unroll
        for (int jj = 0; jj < 4; ++jj) {
          float v = acc[f][cf][jj] + bv;
          if (RELU) v = fmaxf(v, 0.f);
          C[(size_t)(row0 + f * 16 + jj) * N + col0 + cf * 16] = f2bf(v);
        }
      }
    }
  } else {
    float bv[4], wv[4];
#pragma unroll
    for (int cf = 0; cf < 4; ++cf) {
      bv[cf] = bias[col0 + cf * 16];
      wv[cf] = w3[col0 + cf * 16];
    }
#pragma unroll
    for (int f = 0; f < 8; ++f) {
#pragma unroll
      for (int jj = 0; jj < 4; ++jj) {
        float p = 0.f;
#pragma unroll
        for (int cf = 0; cf < 4; ++cf) {
          float v = acc[f][cf][jj] + bv[cf];
          v = fmaxf(v, 0.f);
          p += v * wv[cf];
        }
        p += __shfl_xor(p, 1, 64);
        p += __shfl_xor(p, 2, 64);
        p += __shfl_xor(p, 4, 64);
        p += __shfl_xor(p, 8, 64);
        if (l15 == 0)
          partial[(size_t)(by * 4 + wn) * M + row0 + f * 16 + jj] = p;
      }
    }
  }
}

// =============== stage 9: reduce 16 partials -> sigmoid * keep ===============
__global__ __launch_bounds__(256) void k_head2(const float* __restrict__ partial,
                                               const float* __restrict__ b3,
                                               const float* __restrict__ keepf,
                                               float* __restrict__ scores, int M) {
  int l = blockIdx.x * 256 + threadIdx.x;
  if (l >= NLINES) return;
  float s = 0.f;
#pragma unroll
  for (int i = 0; i < 16; ++i) s += partial[(size_t)i * M + l];
  float logit = s + b3[0];
  scores[l] = keepf[l] / (1.f + expf(-logit));
}

extern "C" void kernel_launch(void* const* d_in, const int* in_sizes, int n_in,
                              void* d_out, int out_size, void* d_ws, size_t ws_size,
                              hipStream_t stream) {
  const float* t_output   = (const float*)d_in[0];
  const float* t_features = (const float*)d_in[1];
  const float* t_lines    = (const float*)d_in[2];
  const float* t_fc1w     = (const float*)d_in[3];
  const float* t_fc1b     = (const float*)d_in[4];
  const float* t_w1       = (const float*)d_in[5];
  const float* t_b1       = (const float*)d_in[6];
  const float* t_w2       = (const float*)d_in[7];
  const float* t_b2       = (const float*)d_in[8];
  const float* t_w3       = (const float*)d_in[9];
  const float* t_b3       = (const float*)d_in[10];

  // workspace layout (~49.5 MB)
  char* w = (char*)d_ws;
  u16*   loib  = (u16*)w;                         // 4 MB
  float* juncs = (float*)(w + 4194304);           // 1024 f32
  float* keepf = juncs + 1024;                    // 10240 f32
  int*   bcnt  = (int*)(keepf + 10240);           // 256 int
  u64*   wkeys = (u64*)(bcnt + 256);              // 16384 u64 = 128 KB
  u16* fc1wb = (u16*)(wkeys + 16384);             // 32768 bf16
  u16* w1b  = fc1wb + 32768;                      // 1M bf16
  u16* w2b  = w1b + 1048576;
  u16* feat = w2b + 1048576;                      // MPAD2*1024 bf16 = 20 MB
  u16* hid1 = feat + (size_t)MPAD2 * 1024;        // 20 MB
  float* partial = (float*)(hid1 + (size_t)MPAD2 * 1024);  // 16*MPAD2 f32
  u16* featT = hid1;                              // alias: consumed before gemm256#1 writes hid1

  float* out_scores = (float*)d_out;
  float* out_ladj   = out_scores + NLINES;
  float* out_juncs  = out_scores + 50000;
  float* out_jsc    = out_scores + 50600;

  k_front1<<<1608, 256, 0, stream>>>(t_output, t_features, t_w1, t_w2, t_fc1w,
                                     featT, w1b, w2b, fc1wb, wkeys, bcnt);
  k_front2<<<129, 1024, 0, stream>>>(wkeys, bcnt, t_output,
                                     juncs, out_juncs, out_jsc,
                                     featT, fc1wb, t_fc1b, loib);
  k_minterp<<<2500, 256, 0, stream>>>(juncs, t_lines, loib, out_ladj, keepf, feat);
  k_gemm256<1, 0><<<dim3(40, 4), 512, 0, stream>>>(feat, w1b, t_b1, hid1,
                                                   nullptr, nullptr, MPAD2, 1024, 1024);
  k_gemm256<0, 1><<<dim3(40, 4), 512, 0, stream>>>(hid1, w2b, t_b2, nullptr,
                                                   t_w3, partial, MPAD2, 1024, 1024);
  k_head2<<<40, 256, 0, stream>>>(partial, t_b3, keepf, out_scores, MPAD2);
}

// Round 11
// 136.103 us; speedup vs baseline: 1.3270x; 1.0674x over previous
//
#include <hip/hip_runtime.h>
#include <stdint.h>

#define HW      16384   // 128*128
#define WIDTH   128
#define NTOPK   300
#define NLINES  10000
#define MPAD2   10240   // 40*256, for 256-tile GEMMs

typedef unsigned short u16;
typedef unsigned int   u32;
typedef unsigned long long u64;
typedef __bf16 bf16x8 __attribute__((ext_vector_type(8)));
typedef float  f32x4  __attribute__((ext_vector_type(4)));

__device__ __forceinline__ u16 f2bf(float f) {
  u32 x = __builtin_bit_cast(u32, f);
  x += 0x7FFFu + ((x >> 16) & 1u);
  return (u16)(x >> 16);
}
__device__ __forceinline__ float bf2f(u32 u) {
  return __builtin_bit_cast(float, u << 16);
}
__device__ __forceinline__ void gload_lds16(void* lds, const void* g) {
  __builtin_amdgcn_global_load_lds(
      (const __attribute__((address_space(1))) void*)g,
      (__attribute__((address_space(3))) void*)lds, 16, 0, 0);
}

#define CF asm volatile("" ::: "memory")
#define BAR do { CF; __builtin_amdgcn_s_barrier(); CF; } while (0)
#define VM4 asm volatile("s_waitcnt vmcnt(4)" ::: "memory")
#define VM0 asm volatile("s_waitcnt vmcnt(0)" ::: "memory")

// bank-spread swizzle for u64 sort keys: bijective (only low-4 bits XORed with
// a function of higher bits); kills same-bank aliasing at power-of-2 strides.
__device__ __forceinline__ int SIDX(int i) {
  return i ^ (((i >> 4) ^ (i >> 8)) & 15);
}

// =============== k_front1: NMS-compact || featT transpose || weight cvt ===============
__global__ __launch_bounds__(256) void k_front1(const float* __restrict__ out9,
                                                const float* __restrict__ features,
                                                const float* __restrict__ w1,
                                                const float* __restrict__ w2,
                                                const float* __restrict__ fc1,
                                                u16* __restrict__ featT,
                                                u16* __restrict__ w1b,
                                                u16* __restrict__ w2b,
                                                u16* __restrict__ fc1wb,
                                                u64* __restrict__ wkeys,
                                                int* __restrict__ bcnt) {
  __shared__ float sm[64 * 65];
  __shared__ int lcnt;
  int b = blockIdx.x, t = threadIdx.x;
  if (b < 64) {
    // ---- NMS-compact ----
    float (*jl)[18] = (float(*)[18])sm;
    if (t == 0) lcnt = 0;
    int bx = b & 7, by = b >> 3;
    int gx0 = bx * 16 - 1, gy0 = by * 16 - 1;
    for (int lin = t; lin < 324; lin += 256) {
      int lx = lin % 18, ly = lin / 18;
      int gx = gx0 + lx, gy = gy0 + ly;
      float v = -__builtin_inff();
      if (gx >= 0 && gx < WIDTH && gy >= 0 && gy < WIDTH) {
        int i = gy * WIDTH + gx;
        v = 1.f / (1.f + expf(out9[5 * HW + i] - out9[6 * HW + i]));
      }
      jl[ly][lx] = v;
    }
    __syncthreads();
    int tx = t & 15, ty = t >> 4;
    float a = jl[ty + 1][tx + 1], m = a;
#pragma unroll
    for (int dy = 0; dy < 3; ++dy)
#pragma unroll
      for (int dx = 0; dx < 3; ++dx)
        m = fmaxf(m, jl[ty + dy][tx + dx]);
    if (a == m) {
      int pos = atomicAdd(&lcnt, 1);
      int i = (by * 16 + ty) * WIDTH + bx * 16 + tx;
      wkeys[b * 256 + pos] =
          ((u64)__builtin_bit_cast(u32, a) << 32) | (u32)(0xFFFFFFFFu - (u32)i);
    }
    __syncthreads();
    if (t == 0) bcnt[b] = lcnt;
  } else if (b < 1088) {
    // ---- transpose ----
    float (*tile)[65] = (float(*)[65])sm;
    int bb = b - 64;
    int p0 = (bb & 255) * 64, c0 = (bb >> 8) * 64;
#pragma unroll
    for (int i = 0; i < 4; ++i) {
      int lin = i * 256 + t;
      int c = lin >> 4, p4 = (lin & 15) * 4;
      float4 v = *(const float4*)&features[(size_t)(c0 + c) * HW + p0 + p4];
      tile[c][p4 + 0] = v.x; tile[c][p4 + 1] = v.y;
      tile[c][p4 + 2] = v.z; tile[c][p4 + 3] = v.w;
    }
    __syncthreads();
#pragma unroll
    for (int i = 0; i < 2; ++i) {
      int lin = i * 256 + t;
      int p = lin >> 3, c8 = (lin & 7) * 8;
      uint4 pk;
      pk.x = (u32)f2bf(tile[c8 + 0][p]) | ((u32)f2bf(tile[c8 + 1][p]) << 16);
      pk.y = (u32)f2bf(tile[c8 + 2][p]) | ((u32)f2bf(tile[c8 + 3][p]) << 16);
      pk.z = (u32)f2bf(tile[c8 + 4][p]) | ((u32)f2bf(tile[c8 + 5][p]) << 16);
      pk.w = (u32)f2bf(tile[c8 + 6][p]) | ((u32)f2bf(tile[c8 + 7][p]) << 16);
      *(uint4*)&featT[(size_t)(p0 + p) * 256 + c0 + c8] = pk;
    }
  } else {
    // ---- weight convert ----
    int idx = b - 1088;
    const float* s; u16* d; int base;
    if (idx < 256)      { s = w1;  d = w1b;  base = idx * 4096; }
    else if (idx < 512) { s = w2;  d = w2b;  base = (idx - 256) * 4096; }
    else                { s = fc1; d = fc1wb; base = (idx - 512) * 4096; }
#pragma unroll
    for (int r = 0; r < 4; ++r) {
      int i = base + r * 1024 + t * 4;
      float4 v = *(const float4*)&s[i];
      uint2 pk;
      pk.x = (u32)f2bf(v.x) | ((u32)f2bf(v.y) << 16);
      pk.y = (u32)f2bf(v.z) | ((u32)f2bf(v.w) << 16);
      *(uint2*)&d[i] = pk;
    }
  }
}

// =============== k_front2 (1024 thr): sort block 0 || loi GEMM blocks 1..128 ===============
// Block 0: wave-parallel gather -> hybrid register/LDS bitonic (j<=64 exchanges
// via __shfl_xor within waves; only j>=128 steps touch LDS) -> emit top-300.
// Blocks 1-128: gemm on waves 0-3 (t<256); waves 4-15 match the 16 __syncthreads.
__global__ __launch_bounds__(1024) void k_front2(const u64* __restrict__ wkeys,
                                                 const int* __restrict__ bcnt,
                                                 const float* __restrict__ out9,
                                                 float* __restrict__ juncs_ws,
                                                 float* __restrict__ out_juncs,
                                                 float* __restrict__ out_jsc,
                                                 const u16* __restrict__ featT,
                                                 const u16* __restrict__ fc1wb,
                                                 const float* __restrict__ fc1b,
                                                 u16* __restrict__ loib) {
  __shared__ u64 smem[4096];     // 32 KB: sort keys / GEMM LDS alias
  __shared__ int scnt[64];
  __shared__ int sbase[65];
  int t = threadIdx.x;
  if (blockIdx.x == 0) {
    u64* keys = smem;
    if (t < 64) scnt[t] = bcnt[t];
    __syncthreads();
    if (t == 0) {
      int s = 0;
      for (int bb = 0; bb < 64; ++bb) { sbase[bb] = s; s += scnt[bb]; }
      sbase[64] = s < 4096 ? s : 4096;
    }
    __syncthreads();
    int total = sbase[64];
    // wave-parallel gather of valid segments (wave w owns bb = w, w+16, w+32, w+48)
    int wv = t >> 6, lane = t & 63;
    for (int bb = wv; bb < 64; bb += 16) {
      int base = sbase[bb], c = scnt[bb];
      for (int i = lane; i < c; i += 64) {
        int d = base + i;
        if (d < 4096) keys[SIDX(d)] = wkeys[bb * 256 + i];
      }
    }
    __syncthreads();
    int n = (total <= 2048) ? 2048 : 4096;
    for (int i = t; i < n; i += 1024)
      if (i >= total) keys[SIDX(i)] = 0ull;
    __syncthreads();
    if (n == 2048) {
      // ---- hybrid bitonic: thread t owns positions 2t, 2t+1 ----
      // phase A: k = 2..128 entirely in registers (all j <= 64), one barrier.
      u64 v0 = keys[SIDX(2 * t)], v1 = keys[SIDX(2 * t + 1)];
#pragma unroll
      for (int k = 2; k <= 128; k <<= 1) {
        bool dir = ((2 * t) & k) == 0;
#pragma unroll
        for (int j = 64; j >= 2; j >>= 1) {
          if (j <= (k >> 1)) {
            int h = j >> 1;
            u64 w0 = __shfl_xor(v0, h, 64);
            u64 w1 = __shfl_xor(v1, h, 64);
            bool first = ((t & h) == 0);
            bool tk0 = first ? ((v0 < w0) == dir) : ((w0 < v0) == dir);
            bool tk1 = first ? ((v1 < w1) == dir) : ((w1 < v1) == dir);
            v0 = tk0 ? w0 : v0;
            v1 = tk1 ? w1 : v1;
          }
        }
        if ((v0 < v1) == dir) { u64 tmp = v0; v0 = v1; v1 = tmp; }
      }
      keys[SIDX(2 * t)] = v0; keys[SIDX(2 * t + 1)] = v1;
      __syncthreads();
      // phase B: k = 256..2048; LDS for j >= 128, registers for j <= 64.
      for (int k = 256; k <= 2048; k <<= 1) {
        for (int j = k >> 1; j >= 128; j >>= 1) {
          int i  = ((t & ~(j - 1)) << 1) | (t & (j - 1));   // n/2 = 1024 = blockDim
          int p  = i | j;
          int si = SIDX(i), sp = SIDX(p);
          u64 a = keys[si], bkey = keys[sp];
          bool dir = (i & k) == 0;
          if ((a < bkey) == dir) { keys[si] = bkey; keys[sp] = a; }
          __syncthreads();
        }
        u64 r0 = keys[SIDX(2 * t)], r1 = keys[SIDX(2 * t + 1)];
        bool dir = ((2 * t) & k) == 0;
#pragma unroll
        for (int j = 64; j >= 2; j >>= 1) {
          int h = j >> 1;
          u64 w0 = __shfl_xor(r0, h, 64);
          u64 w1 = __shfl_xor(r1, h, 64);
          bool first = ((t & h) == 0);
          bool tk0 = first ? ((r0 < w0) == dir) : ((w0 < r0) == dir);
          bool tk1 = first ? ((r1 < w1) == dir) : ((w1 < r1) == dir);
          r0 = tk0 ? w0 : r0;
          r1 = tk1 ? w1 : r1;
        }
        if ((r0 < r1) == dir) { u64 tmp = r0; r0 = r1; r1 = tmp; }
        keys[SIDX(2 * t)] = r0; keys[SIDX(2 * t + 1)] = r1;
        __syncthreads();
      }
    } else {
      // exact fallback (total > 2048): original full-LDS bitonic
      for (int k = 2; k <= n; k <<= 1) {
        for (int j = k >> 1; j > 0; j >>= 1) {
          for (int u = t; u < (n >> 1); u += 1024) {
            int i  = ((u & ~(j - 1)) << 1) | (u & (j - 1));
            int p  = i | j;
            int si = SIDX(i), sp = SIDX(p);
            u64 a = keys[si], bkey = keys[sp];
            bool dir = (i & k) == 0;
            if ((a < bkey) == dir) { keys[si] = bkey; keys[sp] = a; }
          }
          __syncthreads();
        }
      }
    }
    if (t < NTOPK) {
      u64 key = keys[SIDX(t)];
      u32 vb  = (u32)(key >> 32);
      int idx = (int)(0xFFFFFFFFu - (u32)(key & 0xFFFFFFFFu));
      float ox = 1.f / (1.f + expf(-out9[7 * HW + idx])) - 0.5f;
      float oy = 1.f / (1.f + expf(-out9[8 * HW + idx])) - 0.5f;
      float x = (float)(idx & (WIDTH - 1)) + ox + 0.5f;
      float y = (float)(idx >> 7)          + oy + 0.5f;
      juncs_ws[2 * t] = x; juncs_ws[2 * t + 1] = y;
      out_juncs[2 * t] = x; out_juncs[2 * t + 1] = y;
      out_jsc[t] = __builtin_bit_cast(float, vb);
    }
  } else {
    if (t < 256) {
      // ---- loi GEMM (proven m97 structure): M=HW, N=128, K=256 ----
      u16* Alds = (u16*)smem;            // 8 KB
      u16* Blds = (u16*)smem + 4096;     // 8 KB
      const int K = 256, N = 128;
      int bid = blockIdx.x - 1;
      int key = (bid & 7) * 16 + (bid >> 3);   // bijective XCD swizzle, nwg=128
      int tm0 = key * 128;
      int lane = t & 63, wid = t >> 6;
      int wr = wid >> 1, wc = wid & 1;
      f32x4 acc[4][4] = {};
      int arow = t >> 2, apos = (t & 3) * 8;
      const u16* Abase = featT + (size_t)tm0 * K;
      int r = lane & 15, ks = (lane >> 4) * 8;
      for (int k0 = 0; k0 < K; k0 += 32) {
        gload_lds16(&Alds[(size_t)t * 8],         Abase + (size_t)arow * K + k0 + apos);
        gload_lds16(&Alds[(size_t)(t + 256) * 8], Abase + (size_t)(arow + 64) * K + k0 + apos);
        gload_lds16(&Blds[(size_t)t * 8],         fc1wb + (size_t)arow * K + k0 + apos);
        gload_lds16(&Blds[(size_t)(t + 256) * 8], fc1wb + (size_t)(arow + 64) * K + k0 + apos);
        __syncthreads();
        bf16x8 af[4], bfr[4];
#pragma unroll
        for (int i = 0; i < 4; ++i) {
          af[i]  = *(const bf16x8*)&Alds[(wr * 64 + i * 16 + r) * 32 + ks];
          bfr[i] = *(const bf16x8*)&Blds[(wc * 64 + i * 16 + r) * 32 + ks];
        }
#pragma unroll
        for (int mi = 0; mi < 4; ++mi)
#pragma unroll
          for (int ni = 0; ni < 4; ++ni)
            acc[mi][ni] = __builtin_amdgcn_mfma_f32_16x16x32_bf16(af[mi], bfr[ni], acc[mi][ni], 0, 0, 0);
        __syncthreads();
      }
      int rsub = (lane >> 4) * 4, csub = lane & 15;
#pragma unroll
      for (int mi = 0; mi < 4; ++mi) {
#pragma unroll
        for (int ni = 0; ni < 4; ++ni) {
          int col = wc * 64 + ni * 16 + csub;
          float bv = fc1b[col];
#pragma unroll
          for (int j = 0; j < 4; ++j) {
            int row = tm0 + wr * 64 + mi * 16 + rsub + j;
            loib[(size_t)row * N + col] = f2bf(acc[mi][ni][j] + bv);
          }
        }
      }
    } else {
      // idle waves: match the active path's 16 barriers exactly
      for (int i = 0; i < 16; ++i) __syncthreads();
    }
  }
}

// =============== stages 4+6 fused: match + line pooling ===============
__device__ __forceinline__ void acc8(uint4 r, float wg, float* a) {
  a[0] += bf2f(r.x & 0xffffu) * wg; a[1] += bf2f(r.x >> 16) * wg;
  a[2] += bf2f(r.y & 0xffffu) * wg; a[3] += bf2f(r.y >> 16) * wg;
  a[4] += bf2f(r.z & 0xffffu) * wg; a[5] += bf2f(r.z >> 16) * wg;
  a[6] += bf2f(r.w & 0xffffu) * wg; a[7] += bf2f(r.w >> 16) * wg;
}
__global__ __launch_bounds__(256) void k_minterp(const float* __restrict__ juncs,
                                                 const float* __restrict__ lines_pred,
                                                 const u16* __restrict__ loib,
                                                 float* __restrict__ lines_adj,
                                                 float* __restrict__ keepf,
                                                 u16* __restrict__ feat) {
  __shared__ float jl[2 * NTOPK];
  __shared__ u16 outb[4][8][128];
  int t = threadIdx.x;
  for (int i = t; i < 2 * NTOPK; i += 256) jl[i] = juncs[i];
  __syncthreads();
  int w = t >> 6, lane = t & 63;
  int l = blockIdx.x * 4 + w;
  float lx1 = lines_pred[l * 4 + 0], ly1 = lines_pred[l * 4 + 1];
  float lx2 = lines_pred[l * 4 + 2], ly2 = lines_pred[l * 4 + 3];
  float b1 = __builtin_inff(), b2 = __builtin_inff();
  int i1 = 0, i2 = 0;
  for (int j = lane; j < NTOPK; j += 64) {
    float jx = jl[2 * j], jy = jl[2 * j + 1];
    float dx = __fsub_rn(lx1, jx), dy = __fsub_rn(ly1, jy);
    float d  = __fadd_rn(__fmul_rn(dx, dx), __fmul_rn(dy, dy));
    if (d < b1) { b1 = d; i1 = j; }
    dx = __fsub_rn(lx2, jx); dy = __fsub_rn(ly2, jy);
    d  = __fadd_rn(__fmul_rn(dx, dx), __fmul_rn(dy, dy));
    if (d < b2) { b2 = d; i2 = j; }
  }
#pragma unroll
  for (int off = 1; off < 64; off <<= 1) {
    float d_o = __shfl_xor(b1, off, 64); int i_o = __shfl_xor(i1, off, 64);
    if (d_o < b1 || (d_o == b1 && i_o < i1)) { b1 = d_o; i1 = i_o; }
    d_o = __shfl_xor(b2, off, 64); i_o = __shfl_xor(i2, off, 64);
    if (d_o < b2 || (d_o == b2 && i_o < i2)) { b2 = d_o; i2 = i_o; }
  }
  int imin = i1 < i2 ? i1 : i2;
  int imax = i1 < i2 ? i2 : i1;
  float ux = jl[2 * imin], uy = jl[2 * imin + 1];
  float vx = jl[2 * imax], vy = jl[2 * imax + 1];
  if (lane == 0) {
    lines_adj[l * 4 + 0] = ux;
    lines_adj[l * 4 + 1] = uy;
    lines_adj[l * 4 + 2] = vx;
    lines_adj[l * 4 + 3] = vy;
    keepf[l] = (imin < imax) ? 1.f : 0.f;
  }
  int q = lane >> 4, chgrp = lane & 15, co = chgrp * 8;
#pragma unroll
  for (int s = 0; s < 8; ++s) {
    int p = s * 4 + q;
    float tt = (float)p / 31.f;
    float px = ux * tt + vx * (1.f - tt) - 0.5f;
    float py = uy * tt + vy * (1.f - tt) - 0.5f;
    float px0 = fminf(fmaxf(floorf(px), 0.f), 127.f);
    float py0 = fminf(fmaxf(floorf(py), 0.f), 127.f);
    float px1 = fminf(px0 + 1.f, 127.f);
    float py1 = fminf(py0 + 1.f, 127.f);
    int ix0 = (int)px0, iy0 = (int)py0, ix1 = (int)px1, iy1 = (int)py1;
    float wy1 = py1 - py, wy0 = py - py0, wx1 = px1 - px, wx0 = px - px0;
    uint4 v00 = *(const uint4*)&loib[(iy0 * WIDTH + ix0) * 128 + co];
    uint4 v10 = *(const uint4*)&loib[(iy1 * WIDTH + ix0) * 128 + co];
    uint4 v01 = *(const uint4*)&loib[(iy0 * WIDTH + ix1) * 128 + co];
    uint4 v11 = *(const uint4*)&loib[(iy1 * WIDTH + ix1) * 128 + co];
    float a[8];
#pragma unroll
    for (int cc = 0; cc < 8; ++cc) a[cc] = 0.f;
    acc8(v00, wy1 * wx1, a);
    acc8(v10, wy0 * wx1, a);
    acc8(v01, wy1 * wx0, a);
    acc8(v11, wy0 * wx0, a);
#pragma unroll
    for (int cc = 0; cc < 8; ++cc) {
      float v = fmaxf(a[cc], __shfl_xor(a[cc], 16, 64));
      v = fmaxf(v, __shfl_xor(v, 32, 64));
      a[cc] = v;
    }
    if (q == 0) {
      uint4 pk;
      pk.x = (u32)f2bf(a[0]) | ((u32)f2bf(a[1]) << 16);
      pk.y = (u32)f2bf(a[2]) | ((u32)f2bf(a[3]) << 16);
      pk.z = (u32)f2bf(a[4]) | ((u32)f2bf(a[5]) << 16);
      pk.w = (u32)f2bf(a[6]) | ((u32)f2bf(a[7]) << 16);
      *(uint4*)&outb[w][s][co] = pk;
    }
  }
  __syncthreads();
#pragma unroll
  for (int cc = 0; cc < 2; ++cc) {
    int ch = lane * 2 + cc;
    uint4 pk;
    pk.x = (u32)outb[w][0][ch] | ((u32)outb[w][1][ch] << 16);
    pk.y = (u32)outb[w][2][ch] | ((u32)outb[w][3][ch] << 16);
    pk.z = (u32)outb[w][4][ch] | ((u32)outb[w][5][ch] << 16);
    pk.w = (u32)outb[w][6][ch] | ((u32)outb[w][7][ch] << 16);
    *(uint4*)&feat[(size_t)l * 1024 + ch * 8] = pk;
  }
}

// =============== 256-tile 8-phase GEMM (T2+T3+T4+T5) — unchanged ===============
__device__ __forceinline__ void stg256(u16* S, int ldsbase, const u16* Xb,
                                       size_t sbase, int K, int kt, int h, int dbase) {
  gload_lds16(&S[ldsbase + h * 8192 + dbase],
              Xb + sbase + (size_t)(h * 128) * K + kt * 64);
  gload_lds16(&S[ldsbase + h * 8192 + 4096 + dbase],
              Xb + sbase + (size_t)(h * 128 + 64) * K + kt * 64);
}
template <int RH>
__device__ __forceinline__ void lda4(bf16x8 (*dst)[2], const u16* Sa, int rowA,
                                     int kx0, int kx1) {
#pragma unroll
  for (int f = 0; f < 4; ++f) {
    const u16* p = Sa + rowA + (RH * 64 + f * 16) * 64;
    dst[f][0] = *(const bf16x8*)&p[kx0];
    dst[f][1] = *(const bf16x8*)&p[kx1];
  }
}
template <int CH>
__device__ __forceinline__ void ldb2(bf16x8 (*dst)[2], const u16* Sb, int rowB,
                                     int kx0, int kx1) {
#pragma unroll
  for (int cf = 0; cf < 2; ++cf) {
    const u16* p = Sb + rowB + (CH * 32 + cf * 16) * 64;
    dst[cf][0] = *(const bf16x8*)&p[kx0];
    dst[cf][1] = *(const bf16x8*)&p[kx1];
  }
}
template <int RH, int CH>
__device__ __forceinline__ void mm16(f32x4 (*acc)[4], bf16x8 (*af)[2], bf16x8 (*bf)[2]) {
  __builtin_amdgcn_s_setprio(1);
#pragma unroll
  for (int f = 0; f < 4; ++f)
#pragma unroll
    for (int cf = 0; cf < 2; ++cf) {
      f32x4 a = acc[RH * 4 + f][CH * 2 + cf];
      a = __builtin_amdgcn_mfma_f32_16x16x32_bf16(af[f][0], bf[cf][0], a, 0, 0, 0);
      a = __builtin_amdgcn_mfma_f32_16x16x32_bf16(af[f][1], bf[cf][1], a, 0, 0, 0);
      acc[RH * 4 + f][CH * 2 + cf] = a;
    }
  __builtin_amdgcn_s_setprio(0);
}

template <int RELU, int HEAD>
__global__ __launch_bounds__(512, 2) void k_gemm256(const u16* __restrict__ A,
                                                    const u16* __restrict__ B,
                                                    const float* __restrict__ bias,
                                                    u16* __restrict__ C,
                                                    const float* __restrict__ w3,
                                                    float* __restrict__ partial,
                                                    int M, int N, int K) {
  __shared__ u16 S[65536];
  const int t = threadIdx.x, lane = t & 63, w = t >> 6;
  const int wm = w >> 2, wn = w & 3;
  int nwg = gridDim.x * gridDim.y;
  int bid = blockIdx.y * gridDim.x + blockIdx.x;
  int cpx = nwg >> 3;
  int key = (bid & 7) * cpx + (bid >> 3);
  int bx = key / gridDim.y, by = key % gridDim.y;
  const u16* Ab = A + (size_t)(bx * 256) * K;
  const u16* Bb = B + (size_t)(by * 256) * K;
  const int srow = w * 8 + (lane >> 3);
  const size_t sbase = (size_t)srow * K + ((lane & 7) ^ (lane >> 3)) * 8;
  const int dbase = w * 512 + lane * 8;
  const int l15 = lane & 15, hi = lane >> 4, l7 = lane & 7;
  const int rowA = (wm * 128 + l15) * 64;
  const int rowB = (wn * 64 + l15) * 64;
  const int kx0 = ((0 + hi) ^ l7) * 8;
  const int kx1 = ((4 + hi) ^ l7) * 8;
  const u16* SA0 = S;
  const u16* SA1 = S + 16384;
  const u16* SB0 = S + 32768;
  const u16* SB1 = S + 49152;
  f32x4 acc[8][4] = {};
  bf16x8 af0[4][2], af1[4][2], bf0[2][2], bf1[2][2];
  const int NI = K >> 7;
  stg256(S, 0,     Ab, sbase, K, 0, 0, dbase);
  stg256(S, 0,     Ab, sbase, K, 0, 1, dbase);
  stg256(S, 32768, Bb, sbase, K, 0, 0, dbase);
  stg256(S, 32768, Bb, sbase, K, 0, 1, dbase);
  stg256(S, 16384, Ab, sbase, K, 1, 0, dbase);
  stg256(S, 16384, Ab, sbase, K, 1, 1, dbase);
  VM4; BAR;
  for (int j = 0; j < NI - 1; ++j) {
    int kt = 2 * j;
    lda4<0>(af0, SA0, rowA, kx0, kx1);
    ldb2<0>(bf0, SB0, rowB, kx0, kx1);
    stg256(S, 49152, Bb, sbase, K, kt + 1, 0, dbase);
    BAR; mm16<0, 0>(acc, af0, bf0); BAR;
    lda4<1>(af1, SA0, rowA, kx0, kx1);
    stg256(S, 49152, Bb, sbase, K, kt + 1, 1, dbase);
    BAR; mm16<1, 0>(acc, af1, bf0); BAR;
    ldb2<1>(bf1, SB0, rowB, kx0, kx1);
    stg256(S, 0, Ab, sbase, K, kt + 2, 0, dbase);
    BAR; mm16<0, 1>(acc, af0, bf1); BAR;
    stg256(S, 0, Ab, sbase, K, kt + 2, 1, dbase);
    VM4;
    BAR; mm16<1, 1>(acc, af1, bf1); BAR;
    lda4<0>(af0, SA1, rowA, kx0, kx1);
    ldb2<0>(bf0, SB1, rowB, kx0, kx1);
    stg256(S, 32768, Bb, sbase, K, kt + 2, 0, dbase);
    BAR; mm16<0, 0>(acc, af0, bf0); BAR;
    lda4<1>(af1, SA1, rowA, kx0, kx1);
    stg256(S, 32768, Bb, sbase, K, kt + 2, 1, dbase);
    BAR; mm16<1, 0>(acc, af1, bf0); BAR;
    ldb2<1>(bf1, SB1, rowB, kx0, kx1);
    stg256(S, 16384, Ab, sbase, K, kt + 3, 0, dbase);
    BAR; mm16<0, 1>(acc, af0, bf1); BAR;
    stg256(S, 16384, Ab, sbase, K, kt + 3, 1, dbase);
    VM4;
    BAR; mm16<1, 1>(acc, af1, bf1); BAR;
  }
  {
    int kt = 2 * (NI - 1);
    lda4<0>(af0, SA0, rowA, kx0, kx1);
    ldb2<0>(bf0, SB0, rowB, kx0, kx1);
    stg256(S, 49152, Bb, sbase, K, kt + 1, 0, dbase);
    BAR; mm16<0, 0>(acc, af0, bf0); BAR;
    lda4<1>(af1, SA0, rowA, kx0, kx1);
    stg256(S, 49152, Bb, sbase, K, kt + 1, 1, dbase);
    BAR; mm16<1, 0>(acc, af1, bf0); BAR;
    ldb2<1>(bf1, SB0, rowB, kx0, kx1);
    BAR; mm16<0, 1>(acc, af0, bf1); BAR;
    VM0;
    BAR; mm16<1, 1>(acc, af1, bf1); BAR;
    lda4<0>(af0, SA1, rowA, kx0, kx1);
    ldb2<0>(bf0, SB1, rowB, kx0, kx1);
    BAR; mm16<0, 0>(acc, af0, bf0); BAR;
    lda4<1>(af1, SA1, rowA, kx0, kx1);
    BAR; mm16<1, 0>(acc, af1, bf0); BAR;
    ldb2<1>(bf1, SB1, rowB, kx0, kx1);
    BAR; mm16<0, 1>(acc, af0, bf1); BAR;
    mm16<1, 1>(acc, af1, bf1);
  }
  int row0 = bx * 256 + wm * 128 + hi * 4;
  int col0 = by * 256 + wn * 64 + l15;
  if (HEAD == 0) {
#pragma unroll
    for (int f = 0; f < 8; ++f) {
#pragma unroll
      for (int cf = 0; cf < 4; ++cf) {
        float bv = bias[col0 + cf * 16];
#pragma unroll
        for (int jj = 0; jj < 4; ++jj) {
          float v = acc[f][cf][jj] + bv;
          if (RELU) v = fmaxf(v, 0.f);
          C[(size_t)(row0 + f * 16 + jj) * N + col0 + cf * 16] = f2bf(v);
        }
      }
    }
  } else {
    float bv[4], wv[4];
#pragma unroll
    for (int cf = 0; cf < 4; ++cf) {
      bv[cf] = bias[col0 + cf * 16];
      wv[cf] = w3[col0 + cf * 16];
    }
#pragma unroll
    for (int f = 0; f < 8; ++f) {
#pragma unroll
      for (int jj = 0; jj < 4; ++jj) {
        float p = 0.f;
#pragma unroll
        for (int cf = 0; cf < 4; ++cf) {
          float v = acc[f][cf][jj] + bv[cf];
          v = fmaxf(v, 0.f);
          p += v * wv[cf];
        }
        p += __shfl_xor(p, 1, 64);
        p += __shfl_xor(p, 2, 64);
        p += __shfl_xor(p, 4, 64);
        p += __shfl_xor(p, 8, 64);
        if (l15 == 0)
          partial[(size_t)(by * 4 + wn) * M + row0 + f * 16 + jj] = p;
      }
    }
  }
}

// =============== stage 9: reduce 16 partials -> sigmoid * keep ===============
__global__ __launch_bounds__(256) void k_head2(const float* __restrict__ partial,
                                               const float* __restrict__ b3,
                                               const float* __restrict__ keepf,
                                               float* __restrict__ scores, int M) {
  int l = blockIdx.x * 256 + threadIdx.x;
  if (l >= NLINES) return;
  float s = 0.f;
#pragma unroll
  for (int i = 0; i < 16; ++i) s += partial[(size_t)i * M + l];
  float logit = s + b3[0];
  scores[l] = keepf[l] / (1.f + expf(-logit));
}

extern "C" void kernel_launch(void* const* d_in, const int* in_sizes, int n_in,
                              void* d_out, int out_size, void* d_ws, size_t ws_size,
                              hipStream_t stream) {
  const float* t_output   = (const float*)d_in[0];
  const float* t_features = (const float*)d_in[1];
  const float* t_lines    = (const float*)d_in[2];
  const float* t_fc1w     = (const float*)d_in[3];
  const float* t_fc1b     = (const float*)d_in[4];
  const float* t_w1       = (const float*)d_in[5];
  const float* t_b1       = (const float*)d_in[6];
  const float* t_w2       = (const float*)d_in[7];
  const float* t_b2       = (const float*)d_in[8];
  const float* t_w3       = (const float*)d_in[9];
  const float* t_b3       = (const float*)d_in[10];

  // workspace layout (~49.5 MB)
  char* w = (char*)d_ws;
  u16*   loib  = (u16*)w;                         // 4 MB
  float* juncs = (float*)(w + 4194304);           // 1024 f32
  float* keepf = juncs + 1024;                    // 10240 f32
  int*   bcnt  = (int*)(keepf + 10240);           // 256 int
  u64*   wkeys = (u64*)(bcnt + 256);              // 16384 u64 = 128 KB
  u16* fc1wb = (u16*)(wkeys + 16384);             // 32768 bf16
  u16* w1b  = fc1wb + 32768;                      // 1M bf16
  u16* w2b  = w1b + 1048576;
  u16* feat = w2b + 1048576;                      // MPAD2*1024 bf16 = 20 MB
  u16* hid1 = feat + (size_t)MPAD2 * 1024;        // 20 MB
  float* partial = (float*)(hid1 + (size_t)MPAD2 * 1024);  // 16*MPAD2 f32
  u16* featT = hid1;                              // alias: consumed before gemm256#1 writes hid1

  float* out_scores = (float*)d_out;
  float* out_ladj   = out_scores + NLINES;
  float* out_juncs  = out_scores + 50000;
  float* out_jsc    = out_scores + 50600;

  k_front1<<<1608, 256, 0, stream>>>(t_output, t_features, t_w1, t_w2, t_fc1w,
                                     featT, w1b, w2b, fc1wb, wkeys, bcnt);
  k_front2<<<129, 1024, 0, stream>>>(wkeys, bcnt, t_output,
                                     juncs, out_juncs, out_jsc,
                                     featT, fc1wb, t_fc1b, loib);
  k_minterp<<<2500, 256, 0, stream>>>(juncs, t_lines, loib, out_ladj, keepf, feat);
  k_gemm256<1, 0><<<dim3(40, 4), 512, 0, stream>>>(feat, w1b, t_b1, hid1,
                                                   nullptr, nullptr, MPAD2, 1024, 1024);
  k_gemm256<0, 1><<<dim3(40, 4), 512, 0, stream>>>(hid1, w2b, t_b2, nullptr,
                                                   t_w3, partial, MPAD2, 1024, 1024);
  k_head2<<<40, 256, 0, stream>>>(partial, t_b3, keepf, out_scores, MPAD2);
}